// Round 1
// baseline (1073.674 us; speedup 1.0000x reference)
//
#include <hip/hip_runtime.h>
#include <hip/hip_bf16.h>
#include <stdint.h>

#define NN 50000
#define EE 800000
#define HD 64

typedef short short8 __attribute__((ext_vector_type(8)));
typedef float f32x4 __attribute__((ext_vector_type(4)));

__device__ __forceinline__ float b2f(ushort u){ return __uint_as_float(((uint32_t)u)<<16); }
__device__ __forceinline__ ushort f2b(float f){
  uint32_t u = __float_as_uint(f);
  u += 0x7fffu + ((u>>16)&1u);
  return (ushort)(u>>16);
}
__device__ __forceinline__ float silu_f(float x){ return x / (1.0f + __expf(-x)); }

// ---------------- prep kernels ----------------

__global__ __launch_bounds__(256) void k_init(const float* __restrict__ loc,
    const float* __restrict__ vel0, float* __restrict__ coordw,
    float* __restrict__ velw, float* __restrict__ speed0){
  int n = blockIdx.x*256 + threadIdx.x;
  if (n >= NN) return;
  float vx = vel0[n*3+0], vy = vel0[n*3+1], vz = vel0[n*3+2];
  speed0[n] = sqrtf(vx*vx + vy*vy + vz*vz);
  velw[n*3+0]=vx; velw[n*3+1]=vy; velw[n*3+2]=vz;
  coordw[n*3+0]=loc[n*3+0]; coordw[n*3+1]=loc[n*3+1]; coordw[n*3+2]=loc[n*3+2];
}

__global__ __launch_bounds__(256) void k_count(const int* __restrict__ erow, int* __restrict__ counts){
  int e = blockIdx.x*256 + threadIdx.x;
  if (e < EE) atomicAdd(&counts[erow[e]], 1);
}

__global__ __launch_bounds__(1024) void k_scan(const int* __restrict__ counts,
    int* __restrict__ start, int* __restrict__ cursor){
  __shared__ int sm[1024];
  __shared__ int carry;
  int tid = threadIdx.x;
  if (tid == 0) carry = 0;
  __syncthreads();
  for (int base = 0; base < NN; base += 1024){
    int v = (base + tid < NN) ? counts[base + tid] : 0;
    sm[tid] = v;
    __syncthreads();
    for (int off = 1; off < 1024; off <<= 1){
      int t = (tid >= off) ? sm[tid - off] : 0;
      __syncthreads();
      sm[tid] += t;
      __syncthreads();
    }
    int excl = sm[tid] - v + carry;
    if (base + tid < NN){ start[base + tid] = excl; cursor[base + tid] = excl; }
    __syncthreads();
    if (tid == 1023) carry += sm[1023];
    __syncthreads();
  }
  if (tid == 0) start[NN] = EE;
}

__global__ __launch_bounds__(256) void k_fill(const int* __restrict__ erow,
    int* __restrict__ cursor, int* __restrict__ eids){
  int e = blockIdx.x*256 + threadIdx.x;
  if (e < EE){
    int pos = atomicAdd(&cursor[erow[e]], 1);
    eids[pos] = e;
  }
}

// pack weight [Ksrc,64] into MFMA B-frag order: ((kt*4+ct)*64+lane)*8+i
__global__ __launch_bounds__(256) void k_pack(const float* __restrict__ src,
    ushort* __restrict__ dst, int Ksrc, int ktTotal){
  int idx = blockIdx.x*256 + threadIdx.x;
  if (idx >= ktTotal*2048) return;
  int i = idx & 7;
  int lane = (idx >> 3) & 63;
  int ctkt = idx >> 9;
  int ct = ctkt & 3, kt = ctkt >> 2;
  int k = kt*32 + (lane>>4)*8 + i;
  int col = ct*16 + (lane & 15);
  float v = (k < Ksrc) ? src[k*64 + col] : 0.0f;
  dst[idx] = f2b(v);
}

__global__ __launch_bounds__(256) void k_embed(const float* __restrict__ his,
    const float* __restrict__ embW, const float* __restrict__ embB,
    float* __restrict__ h, ushort* __restrict__ hb){
  int idx = blockIdx.x*256 + threadIdx.x;
  if (idx >= NN*HD) return;
  int n = idx >> 6, j = idx & 63;
  float s = embB[j];
  #pragma unroll
  for (int k = 0; k < 8; ++k) s += his[n*8 + k] * embW[k*64 + j];
  h[idx] = s;
  hb[idx] = f2b(s);
}

// ---------------- edge MFMA kernel ----------------
// block = 256 thr = 4 waves, 64 edges/block, 16 edges/wave.
template<int MAT>
__global__ __launch_bounds__(256) void k_edge(
    const ushort* __restrict__ hb, const float* __restrict__ coord,
    const int* __restrict__ erow, const int* __restrict__ ecol,
    const float* __restrict__ eattr,
    const ushort* __restrict__ W1p, const ushort* __restrict__ W2p, const ushort* __restrict__ cW1p,
    const float* __restrict__ b1, const float* __restrict__ b2,
    const float* __restrict__ cb1, const float* __restrict__ cw2,
    ushort* __restrict__ m_out, float* __restrict__ accnum, float* __restrict__ aggf)
{
  __shared__ __align__(16) ushort X1[64*88];
  __shared__ __align__(16) ushort ML[64*88];
  __shared__ float WL[64];
  const int tid = threadIdx.x;
  const int wave = tid >> 6, lane = tid & 63;
  const int c = lane & 15, g = lane >> 4;
  const int wt = wave * 16;
  const int ebase = blockIdx.x * 64;
  const int eA = ebase + wt + c;
  const int rA = erow[eA], cA = ecol[eA];

  // A fragments for GEMM1 (K=160): h[row](64) | h[col](64) | radial,ea0,ea1,pad(32)
  short8 a0 = *reinterpret_cast<const short8*>(hb + (size_t)rA*HD + g*8);
  short8 a1 = *reinterpret_cast<const short8*>(hb + (size_t)rA*HD + 32 + g*8);
  short8 a2 = *reinterpret_cast<const short8*>(hb + (size_t)cA*HD + g*8);
  short8 a3 = *reinterpret_cast<const short8*>(hb + (size_t)cA*HD + 32 + g*8);
  float dx = coord[rA*3+0] - coord[cA*3+0];
  float dy = coord[rA*3+1] - coord[cA*3+1];
  float dz = coord[rA*3+2] - coord[cA*3+2];
  float radial = dx*dx + dy*dy + dz*dz;
  short8 a4 = {0,0,0,0,0,0,0,0};
  if (g == 0){
    a4[0] = (short)f2b(radial);
    a4[1] = (short)f2b(eattr[(size_t)eA*2 + 0]);
    a4[2] = (short)f2b(eattr[(size_t)eA*2 + 1]);
  }
  short8 af[5] = {a0, a1, a2, a3, a4};
  const short8* W1f = reinterpret_cast<const short8*>(W1p);
  const short8* W2f = reinterpret_cast<const short8*>(W2p);
  const short8* C1f = reinterpret_cast<const short8*>(cW1p);

  f32x4 zero = {0.f,0.f,0.f,0.f};
  f32x4 acc[4] = {zero,zero,zero,zero};
  #pragma unroll
  for (int kt = 0; kt < 5; ++kt){
    #pragma unroll
    for (int ct = 0; ct < 4; ++ct){
      acc[ct] = __builtin_amdgcn_mfma_f32_16x16x32_bf16(af[kt], W1f[(kt*4+ct)*64 + lane], acc[ct], 0,0,0);
    }
  }
  // X1 = silu(acc + b1) -> LDS (edge-row major, stride 88)
  #pragma unroll
  for (int ct = 0; ct < 4; ++ct){
    int col = ct*16 + c;
    float bias = b1[col];
    #pragma unroll
    for (int r = 0; r < 4; ++r){
      X1[(wt + g*4 + r)*88 + col] = f2b(silu_f(acc[ct][r] + bias));
    }
  }
  __syncthreads();

  // GEMM2: m = silu(X1 @ W2 + b2)
  f32x4 acc2[4] = {zero,zero,zero,zero};
  #pragma unroll
  for (int kt = 0; kt < 2; ++kt){
    short8 a = *reinterpret_cast<const short8*>(&X1[(wt + c)*88 + kt*32 + g*8]);
    #pragma unroll
    for (int ct = 0; ct < 4; ++ct){
      acc2[ct] = __builtin_amdgcn_mfma_f32_16x16x32_bf16(a, W2f[(kt*4+ct)*64 + lane], acc2[ct], 0,0,0);
    }
  }
  #pragma unroll
  for (int ct = 0; ct < 4; ++ct){
    int col = ct*16 + c;
    float bias = b2[col];
    #pragma unroll
    for (int r = 0; r < 4; ++r){
      ML[(wt + g*4 + r)*88 + col] = f2b(silu_f(acc2[ct][r] + bias));
    }
  }
  __syncthreads();

  // GEMM3: X3 = silu(m @ cW1 + cb1); w = X3 @ cW2
  f32x4 acc3[4] = {zero,zero,zero,zero};
  #pragma unroll
  for (int kt = 0; kt < 2; ++kt){
    short8 a = *reinterpret_cast<const short8*>(&ML[(wt + c)*88 + kt*32 + g*8]);
    #pragma unroll
    for (int ct = 0; ct < 4; ++ct){
      acc3[ct] = __builtin_amdgcn_mfma_f32_16x16x32_bf16(a, C1f[(kt*4+ct)*64 + lane], acc3[ct], 0,0,0);
    }
  }
  float pw[4] = {0.f,0.f,0.f,0.f};
  #pragma unroll
  for (int ct = 0; ct < 4; ++ct){
    int col = ct*16 + c;
    float cb = cb1[col];
    float cw = cw2[col];
    #pragma unroll
    for (int r = 0; r < 4; ++r) pw[r] += silu_f(acc3[ct][r] + cb) * cw;
  }
  #pragma unroll
  for (int off = 1; off < 16; off <<= 1){
    #pragma unroll
    for (int r = 0; r < 4; ++r) pw[r] += __shfl_xor(pw[r], off, 16);
  }
  if (c == 0){
    #pragma unroll
    for (int r = 0; r < 4; ++r) WL[wt + g*4 + r] = pw[r];
  }
  __syncthreads();

  // trans scatter: 16 edges * 3 axes per wave
  if (lane < 48){
    int el = lane / 3, ax = lane - el*3;
    int e = ebase + wt + el;
    int rr = erow[e], cc = ecol[e];
    float cd = coord[rr*3 + ax] - coord[cc*3 + ax];
    atomicAdd(&accnum[rr*3 + ax], cd * WL[wt + el]);
  }

  // m output
  int el = lane >> 2, q = lane & 3;
  #pragma unroll
  for (int it = 0; it < 2; ++it){
    int k = it*32 + q*8;
    if (MAT){
      uint4 v = *reinterpret_cast<const uint4*>(&ML[(wt + el)*88 + k]);
      *reinterpret_cast<uint4*>(m_out + (size_t)(ebase + wt + el)*HD + k) = v;
    } else {
      int rowi = erow[ebase + wt + el];
      const ushort* src = &ML[(wt + el)*88 + k];
      #pragma unroll
      for (int i = 0; i < 8; ++i) atomicAdd(&aggf[(size_t)rowi*HD + k + i], b2f(src[i]));
    }
  }
}

// ---------------- aggregation ----------------
__global__ __launch_bounds__(256) void k_agg(const ushort* __restrict__ m,
    const int* __restrict__ start, const int* __restrict__ eids, ushort* __restrict__ aggb){
  int wave = threadIdx.x >> 6, lane = threadIdx.x & 63;
  int node = blockIdx.x*4 + wave;
  if (node >= NN) return;
  int s0 = start[node], s1 = start[node+1];
  float sum = 0.f;
  for (int t = s0; t < s1; ++t){
    int eid = eids[t];
    sum += b2f(m[(size_t)eid*HD + lane]);
  }
  aggb[(size_t)node*HD + lane] = f2b(sum);
}

__global__ __launch_bounds__(256) void k_aggconv(const float* __restrict__ aggf, ushort* __restrict__ aggb){
  int idx = blockIdx.x*256 + threadIdx.x;
  if (idx < NN*HD) aggb[idx] = f2b(aggf[idx]);
}

// ---------------- node MFMA kernel ----------------
__global__ __launch_bounds__(256) void k_node(
    const ushort* __restrict__ hb, const ushort* __restrict__ aggb, const float* __restrict__ h_in,
    const ushort* __restrict__ nW1p, const ushort* __restrict__ nW2p, const ushort* __restrict__ vW1p,
    const float* __restrict__ nb1, const float* __restrict__ nb2,
    const float* __restrict__ vb1, const float* __restrict__ vW2, const float* __restrict__ vb2,
    float* __restrict__ h_out, ushort* __restrict__ hb_out, float* __restrict__ vs_out)
{
  __shared__ __align__(16) ushort HID[64*88];
  const int tid = threadIdx.x;
  const int wave = tid >> 6, lane = tid & 63;
  const int c = lane & 15, g = lane >> 4;
  const int wt = wave * 16;
  const int nbase = blockIdx.x * 64;
  int nA = nbase + wt + c;
  int nAc = (nA < NN) ? nA : (NN-1);

  short8 af[4];
  af[0] = *reinterpret_cast<const short8*>(hb   + (size_t)nAc*HD + g*8);
  af[1] = *reinterpret_cast<const short8*>(hb   + (size_t)nAc*HD + 32 + g*8);
  af[2] = *reinterpret_cast<const short8*>(aggb + (size_t)nAc*HD + g*8);
  af[3] = *reinterpret_cast<const short8*>(aggb + (size_t)nAc*HD + 32 + g*8);
  const short8* N1f = reinterpret_cast<const short8*>(nW1p);
  const short8* N2f = reinterpret_cast<const short8*>(nW2p);
  const short8* V1f = reinterpret_cast<const short8*>(vW1p);

  f32x4 zero = {0.f,0.f,0.f,0.f};
  f32x4 acc[4] = {zero,zero,zero,zero};
  #pragma unroll
  for (int kt = 0; kt < 4; ++kt){
    #pragma unroll
    for (int ct = 0; ct < 4; ++ct){
      acc[ct] = __builtin_amdgcn_mfma_f32_16x16x32_bf16(af[kt], N1f[(kt*4+ct)*64 + lane], acc[ct], 0,0,0);
    }
  }
  #pragma unroll
  for (int ct = 0; ct < 4; ++ct){
    int col = ct*16 + c;
    float bias = nb1[col];
    #pragma unroll
    for (int r = 0; r < 4; ++r){
      HID[(wt + g*4 + r)*88 + col] = f2b(silu_f(acc[ct][r] + bias));
    }
  }
  __syncthreads();

  // v MLP (uses h only)
  f32x4 av[4] = {zero,zero,zero,zero};
  #pragma unroll
  for (int kt = 0; kt < 2; ++kt){
    #pragma unroll
    for (int ct = 0; ct < 4; ++ct){
      av[ct] = __builtin_amdgcn_mfma_f32_16x16x32_bf16(af[kt], V1f[(kt*4+ct)*64 + lane], av[ct], 0,0,0);
    }
  }
  float pw[4] = {0.f,0.f,0.f,0.f};
  #pragma unroll
  for (int ct = 0; ct < 4; ++ct){
    int col = ct*16 + c;
    float vb = vb1[col];
    float vw = vW2[col];
    #pragma unroll
    for (int r = 0; r < 4; ++r) pw[r] += silu_f(av[ct][r] + vb) * vw;
  }
  #pragma unroll
  for (int off = 1; off < 16; off <<= 1){
    #pragma unroll
    for (int r = 0; r < 4; ++r) pw[r] += __shfl_xor(pw[r], off, 16);
  }
  if (c == 0){
    float vbias = vb2[0];
    #pragma unroll
    for (int r = 0; r < 4; ++r){
      int n = nbase + wt + g*4 + r;
      if (n < NN) vs_out[n] = pw[r] + vbias;
    }
  }

  // node MLP second layer
  f32x4 a2[4] = {zero,zero,zero,zero};
  #pragma unroll
  for (int kt = 0; kt < 2; ++kt){
    short8 a = *reinterpret_cast<const short8*>(&HID[(wt + c)*88 + kt*32 + g*8]);
    #pragma unroll
    for (int ct = 0; ct < 4; ++ct){
      a2[ct] = __builtin_amdgcn_mfma_f32_16x16x32_bf16(a, N2f[(kt*4+ct)*64 + lane], a2[ct], 0,0,0);
    }
  }
  #pragma unroll
  for (int ct = 0; ct < 4; ++ct){
    int col = ct*16 + c;
    float bias = nb2[col];
    #pragma unroll
    for (int r = 0; r < 4; ++r){
      int n = nbase + wt + g*4 + r;
      if (n < NN){
        size_t off = (size_t)n*HD + col;
        float v = 2.0f*h_in[off] + a2[ct][r] + bias;
        h_out[off] = v;
        hb_out[off] = f2b(v);
      }
    }
  }
}

// ---------------- vel / coord update ----------------
__global__ __launch_bounds__(256) void k_velcoord(const float* __restrict__ accnum,
    const int* __restrict__ counts, const float* __restrict__ vs,
    const float* __restrict__ vel_in, const float* __restrict__ coord_in,
    const float* __restrict__ speed0, float* __restrict__ vel_out, float* __restrict__ coord_out)
{
  int n = blockIdx.x*256 + threadIdx.x;
  if (n >= NN) return;
  float dn = fmaxf((float)counts[n], 1.0f);
  float vsn = vs[n];
  float v[3];
  float norm2 = 0.f;
  #pragma unroll
  for (int ax = 0; ax < 3; ++ax){
    float a = accnum[n*3 + ax] / dn;
    float vv = vsn * vel_in[n*3 + ax] + a / 7.0f;
    v[ax] = vv;
    norm2 += vv*vv;
  }
  float s = speed0[n] / (sqrtf(norm2) + 1e-8f);
  #pragma unroll
  for (int ax = 0; ax < 3; ++ax){
    float vo = v[ax] * s;
    vel_out[n*3 + ax] = vo;
    coord_out[n*3 + ax] = coord_in[n*3 + ax] + vo / 7.0f;
  }
}

// ---------------- launcher ----------------
extern "C" void kernel_launch(void* const* d_in, const int* in_sizes, int n_in,
                              void* d_out, int out_size, void* d_ws, size_t ws_size,
                              hipStream_t stream)
{
  const float* his  = (const float*)d_in[0];
  const float* loc  = (const float*)d_in[1];
  const int*   edges= (const int*)d_in[2];
  const float* vel0 = (const float*)d_in[3];
  const float* eatt = (const float*)d_in[4];
  const float* embW = (const float*)d_in[5];
  const float* embB = (const float*)d_in[6];
  const float* eW1  = (const float*)d_in[7];
  const float* eB1  = (const float*)d_in[8];
  const float* eW2  = (const float*)d_in[9];
  const float* eB2  = (const float*)d_in[10];
  const float* cW1  = (const float*)d_in[11];
  const float* cB1  = (const float*)d_in[12];
  const float* cW2  = (const float*)d_in[13];
  const float* vW1  = (const float*)d_in[14];
  const float* vB1  = (const float*)d_in[15];
  const float* vW2  = (const float*)d_in[16];
  const float* vB2  = (const float*)d_in[17];
  const float* nW1  = (const float*)d_in[18];
  const float* nB1  = (const float*)d_in[19];
  const float* nW2  = (const float*)d_in[20];
  const float* nB2  = (const float*)d_in[21];
  const int* erow = edges;
  const int* ecol = edges + EE;

  char* ws = (char*)d_ws;
  size_t off = 0;
  auto alloc = [&](size_t bytes)->char*{
    char* p = ws + off;
    off = (off + bytes + 255) & ~(size_t)255;
    return p;
  };
  float*  h      = (float*) alloc((size_t)NN*HD*4);
  ushort* hb     = (ushort*)alloc((size_t)NN*HD*2);
  ushort* aggb   = (ushort*)alloc((size_t)NN*HD*2);
  float*  accnum = (float*) alloc((size_t)NN*3*4);
  int*    counts = (int*)   alloc((size_t)NN*4);
  int*    cursor = (int*)   alloc((size_t)NN*4);
  int*    startp = (int*)   alloc((size_t)(NN+1)*4);
  int*    eids   = (int*)   alloc((size_t)EE*4);
  float*  coordw = (float*) alloc((size_t)NN*3*4);
  float*  velw   = (float*) alloc((size_t)NN*3*4);
  float*  speed0 = (float*) alloc((size_t)NN*4);
  float*  vs     = (float*) alloc((size_t)NN*4);
  ushort* W1p    = (ushort*)alloc(5*2048*2);
  ushort* W2p    = (ushort*)alloc(2*2048*2);
  ushort* cW1p   = (ushort*)alloc(2*2048*2);
  ushort* nW1p   = (ushort*)alloc(4*2048*2);
  ushort* nW2p   = (ushort*)alloc(2*2048*2);
  ushort* vW1p   = (ushort*)alloc(2*2048*2);
  size_t base_need = off;
  bool mat = (ws_size >= base_need + (size_t)EE*HD*2 + 256);
  ushort* mbuf = nullptr;
  float* aggf = nullptr;
  if (mat) mbuf = (ushort*)alloc((size_t)EE*HD*2);
  else     aggf = (float*)alloc((size_t)NN*HD*4);

  float* xout = (float*)d_out;                    // [N,3]
  float* hout = (float*)d_out + (size_t)NN*3;     // [N,64]
  float* vout = (float*)d_out + (size_t)NN*3 + (size_t)NN*HD; // [N,3]

  hipMemsetAsync(counts, 0, (size_t)NN*4, stream);
  k_init<<<196,256,0,stream>>>(loc, vel0, coordw, velw, speed0);
  k_count<<<3125,256,0,stream>>>(erow, counts);
  k_scan<<<1,1024,0,stream>>>(counts, startp, cursor);
  k_fill<<<3125,256,0,stream>>>(erow, cursor, eids);
  k_pack<<<40,256,0,stream>>>(eW1, W1p, 131, 5);
  k_pack<<<16,256,0,stream>>>(eW2, W2p, 64, 2);
  k_pack<<<16,256,0,stream>>>(cW1, cW1p, 64, 2);
  k_pack<<<32,256,0,stream>>>(nW1, nW1p, 128, 4);
  k_pack<<<16,256,0,stream>>>(nW2, nW2p, 64, 2);
  k_pack<<<16,256,0,stream>>>(vW1, vW1p, 64, 2);
  k_embed<<<12500,256,0,stream>>>(his, embW, embB, h, hb);

  for (int L = 0; L < 4; ++L){
    hipMemsetAsync(accnum, 0, (size_t)NN*3*4, stream);
    if (mat){
      k_edge<1><<<12500,256,0,stream>>>(hb, coordw, erow, ecol, eatt,
          W1p, W2p, cW1p, eB1, eB2, cB1, cW2, mbuf, accnum, nullptr);
      k_agg<<<12500,256,0,stream>>>(mbuf, startp, eids, aggb);
    } else {
      hipMemsetAsync(aggf, 0, (size_t)NN*HD*4, stream);
      k_edge<0><<<12500,256,0,stream>>>(hb, coordw, erow, ecol, eatt,
          W1p, W2p, cW1p, eB1, eB2, cB1, cW2, nullptr, accnum, aggf);
      k_aggconv<<<12500,256,0,stream>>>(aggf, aggb);
    }
    float* h_o = (L == 3) ? hout : h;
    k_node<<<782,256,0,stream>>>(hb, aggb, h, nW1p, nW2p, vW1p,
        nB1, nB2, vB1, vW2, vB2, h_o, hb, vs);
    float* v_o = (L == 3) ? vout : velw;
    float* c_o = (L == 3) ? xout : coordw;
    k_velcoord<<<196,256,0,stream>>>(accnum, counts, vs, velw, coordw, speed0, v_o, c_o);
  }
}

// Round 2
// 798.878 us; speedup vs baseline: 1.3440x; 1.3440x over previous
//
#include <hip/hip_runtime.h>
#include <hip/hip_bf16.h>
#include <stdint.h>

#define NN 50000
#define EE 800000
#define HD 64

typedef short short8 __attribute__((ext_vector_type(8)));
typedef float f32x4 __attribute__((ext_vector_type(4)));

__device__ __forceinline__ float b2f(ushort u){ return __uint_as_float(((uint32_t)u)<<16); }
__device__ __forceinline__ ushort f2b(float f){
  uint32_t u = __float_as_uint(f);
  u += 0x7fffu + ((u>>16)&1u);
  return (ushort)(u>>16);
}
__device__ __forceinline__ float silu_f(float x){ return x / (1.0f + __expf(-x)); }

// ---------------- prep kernels ----------------

__global__ __launch_bounds__(256) void k_init(const float* __restrict__ loc,
    const float* __restrict__ vel0, float* __restrict__ coordw,
    float* __restrict__ velw, float* __restrict__ speed0){
  int n = blockIdx.x*256 + threadIdx.x;
  if (n >= NN) return;
  float vx = vel0[n*3+0], vy = vel0[n*3+1], vz = vel0[n*3+2];
  speed0[n] = sqrtf(vx*vx + vy*vy + vz*vz);
  velw[n*3+0]=vx; velw[n*3+1]=vy; velw[n*3+2]=vz;
  coordw[n*3+0]=loc[n*3+0]; coordw[n*3+1]=loc[n*3+1]; coordw[n*3+2]=loc[n*3+2];
}

__global__ __launch_bounds__(256) void k_count(const int* __restrict__ erow, int* __restrict__ counts){
  int e = blockIdx.x*256 + threadIdx.x;
  if (e < EE) atomicAdd(&counts[erow[e]], 1);
}

__global__ __launch_bounds__(1024) void k_scan(const int* __restrict__ counts,
    int* __restrict__ start, int* __restrict__ cursor){
  __shared__ int sm[1024];
  __shared__ int carry;
  int tid = threadIdx.x;
  if (tid == 0) carry = 0;
  __syncthreads();
  for (int base = 0; base < NN; base += 1024){
    int v = (base + tid < NN) ? counts[base + tid] : 0;
    sm[tid] = v;
    __syncthreads();
    for (int off = 1; off < 1024; off <<= 1){
      int t = (tid >= off) ? sm[tid - off] : 0;
      __syncthreads();
      sm[tid] += t;
      __syncthreads();
    }
    int excl = sm[tid] - v + carry;
    if (base + tid < NN){ start[base + tid] = excl; cursor[base + tid] = excl; }
    __syncthreads();
    if (tid == 1023) carry += sm[1023];
    __syncthreads();
  }
  if (tid == 0) start[NN] = EE;
}

// build CSR-sorted edge records {row, col, ea0, ea1}
__global__ __launch_bounds__(256) void k_fill(const int* __restrict__ erow,
    const int* __restrict__ ecol, const float* __restrict__ eattr,
    int* __restrict__ cursor, int4* __restrict__ erec){
  int e = blockIdx.x*256 + threadIdx.x;
  if (e < EE){
    int r = erow[e];
    int pos = atomicAdd(&cursor[r], 1);
    int4 rec;
    rec.x = r;
    rec.y = ecol[e];
    rec.z = __float_as_int(eattr[(size_t)e*2 + 0]);
    rec.w = __float_as_int(eattr[(size_t)e*2 + 1]);
    erec[pos] = rec;
  }
}

// pack weight [Ksrc,64] into MFMA B-frag order: ((kt*4+ct)*64+lane)*8+i
__global__ __launch_bounds__(256) void k_pack(const float* __restrict__ src,
    ushort* __restrict__ dst, int Ksrc, int ktTotal){
  int idx = blockIdx.x*256 + threadIdx.x;
  if (idx >= ktTotal*2048) return;
  int i = idx & 7;
  int lane = (idx >> 3) & 63;
  int ctkt = idx >> 9;
  int ct = ctkt & 3, kt = ctkt >> 2;
  int k = kt*32 + (lane>>4)*8 + i;
  int col = ct*16 + (lane & 15);
  float v = (k < Ksrc) ? src[k*64 + col] : 0.0f;
  dst[idx] = f2b(v);
}

__global__ __launch_bounds__(256) void k_embed(const float* __restrict__ his,
    const float* __restrict__ embW, const float* __restrict__ embB,
    float* __restrict__ h, ushort* __restrict__ hb){
  int idx = blockIdx.x*256 + threadIdx.x;
  if (idx >= NN*HD) return;
  int n = idx >> 6, j = idx & 63;
  float s = embB[j];
  #pragma unroll
  for (int k = 0; k < 8; ++k) s += his[n*8 + k] * embW[k*64 + j];
  h[idx] = s;
  hb[idx] = f2b(s);
}

// ---------------- edge MFMA kernel (barrier-free, wave-private LDS) ----------------
__global__ __launch_bounds__(256) void k_edge(
    const ushort* __restrict__ hb, const float* __restrict__ coord,
    const int4* __restrict__ erec,
    const ushort* __restrict__ W1p, const ushort* __restrict__ W2p, const ushort* __restrict__ cW1p,
    const float* __restrict__ b1, const float* __restrict__ b2,
    const float* __restrict__ cb1, const float* __restrict__ cw2,
    ushort* __restrict__ m_out, float* __restrict__ trans_out)
{
  __shared__ __align__(16) ushort XM[64*88];   // X1, then ML (aliased; wave-private rows)
  __shared__ float WL[64];
  const int tid = threadIdx.x;
  const int wave = tid >> 6, lane = tid & 63;
  const int c = lane & 15, g = lane >> 4;
  const int wt = wave * 16;
  const int slot = blockIdx.x*64 + wt + c;

  int4 er = erec[slot];
  const int rA = er.x, cA = er.y;
  float ea0 = __int_as_float(er.z), ea1 = __int_as_float(er.w);

  short8 af[5];
  af[0] = *reinterpret_cast<const short8*>(hb + (size_t)rA*HD + g*8);
  af[1] = *reinterpret_cast<const short8*>(hb + (size_t)rA*HD + 32 + g*8);
  af[2] = *reinterpret_cast<const short8*>(hb + (size_t)cA*HD + g*8);
  af[3] = *reinterpret_cast<const short8*>(hb + (size_t)cA*HD + 32 + g*8);
  float dx = coord[rA*3+0] - coord[cA*3+0];
  float dy = coord[rA*3+1] - coord[cA*3+1];
  float dz = coord[rA*3+2] - coord[cA*3+2];
  float radial = dx*dx + dy*dy + dz*dz;
  short8 a4 = {0,0,0,0,0,0,0,0};
  if (g == 0){
    a4[0] = (short)f2b(radial);
    a4[1] = (short)f2b(ea0);
    a4[2] = (short)f2b(ea1);
  }
  af[4] = a4;

  const short8* W1f = reinterpret_cast<const short8*>(W1p);
  const short8* W2f = reinterpret_cast<const short8*>(W2p);
  const short8* C1f = reinterpret_cast<const short8*>(cW1p);

  // GEMM1: X1 = silu(e_in @ W1 + b1)   (bias folded into acc init)
  f32x4 acc[4];
  #pragma unroll
  for (int ct = 0; ct < 4; ++ct){
    float bb = b1[ct*16 + c];
    acc[ct] = (f32x4){bb,bb,bb,bb};
  }
  #pragma unroll
  for (int kt = 0; kt < 5; ++kt){
    #pragma unroll
    for (int ct = 0; ct < 4; ++ct){
      acc[ct] = __builtin_amdgcn_mfma_f32_16x16x32_bf16(af[kt], W1f[(kt*4+ct)*64 + lane], acc[ct], 0,0,0);
    }
  }
  #pragma unroll
  for (int ct = 0; ct < 4; ++ct){
    int col = ct*16 + c;
    #pragma unroll
    for (int r = 0; r < 4; ++r){
      XM[(wt + g*4 + r)*88 + col] = f2b(silu_f(acc[ct][r]));
    }
  }
  // in-wave transpose read (DS ops are in-order per wave; no barrier needed)
  short8 xa0 = *reinterpret_cast<const short8*>(&XM[(wt + c)*88 + g*8]);
  short8 xa1 = *reinterpret_cast<const short8*>(&XM[(wt + c)*88 + 32 + g*8]);

  // GEMM2: m = silu(X1 @ W2 + b2)
  f32x4 acc2[4];
  #pragma unroll
  for (int ct = 0; ct < 4; ++ct){
    float bb = b2[ct*16 + c];
    acc2[ct] = (f32x4){bb,bb,bb,bb};
  }
  #pragma unroll
  for (int ct = 0; ct < 4; ++ct)
    acc2[ct] = __builtin_amdgcn_mfma_f32_16x16x32_bf16(xa0, W2f[(0*4+ct)*64 + lane], acc2[ct], 0,0,0);
  #pragma unroll
  for (int ct = 0; ct < 4; ++ct)
    acc2[ct] = __builtin_amdgcn_mfma_f32_16x16x32_bf16(xa1, W2f[(1*4+ct)*64 + lane], acc2[ct], 0,0,0);
  #pragma unroll
  for (int ct = 0; ct < 4; ++ct){
    int col = ct*16 + c;
    #pragma unroll
    for (int r = 0; r < 4; ++r){
      XM[(wt + g*4 + r)*88 + col] = f2b(silu_f(acc2[ct][r]));
    }
  }
  short8 ma0 = *reinterpret_cast<const short8*>(&XM[(wt + c)*88 + g*8]);
  short8 ma1 = *reinterpret_cast<const short8*>(&XM[(wt + c)*88 + 32 + g*8]);

  // GEMM3: X3 = silu(m @ cW1 + cb1); w = X3 @ cW2
  f32x4 acc3[4];
  #pragma unroll
  for (int ct = 0; ct < 4; ++ct){
    float bb = cb1[ct*16 + c];
    acc3[ct] = (f32x4){bb,bb,bb,bb};
  }
  #pragma unroll
  for (int ct = 0; ct < 4; ++ct)
    acc3[ct] = __builtin_amdgcn_mfma_f32_16x16x32_bf16(ma0, C1f[(0*4+ct)*64 + lane], acc3[ct], 0,0,0);
  #pragma unroll
  for (int ct = 0; ct < 4; ++ct)
    acc3[ct] = __builtin_amdgcn_mfma_f32_16x16x32_bf16(ma1, C1f[(1*4+ct)*64 + lane], acc3[ct], 0,0,0);

  float pw[4] = {0.f,0.f,0.f,0.f};
  #pragma unroll
  for (int ct = 0; ct < 4; ++ct){
    int col = ct*16 + c;
    float cw = cw2[col];
    #pragma unroll
    for (int r = 0; r < 4; ++r) pw[r] += silu_f(acc3[ct][r]) * cw;
  }
  #pragma unroll
  for (int off = 1; off < 16; off <<= 1){
    #pragma unroll
    for (int r = 0; r < 4; ++r) pw[r] += __shfl_xor(pw[r], off, 16);
  }
  if (c == 0){
    #pragma unroll
    for (int r = 0; r < 4; ++r) WL[wt + g*4 + r] = pw[r];
  }
  float w = WL[wt + c];       // in-wave LDS transpose of w
  if (g == 0){
    f32x4 t = {dx*w, dy*w, dz*w, 0.0f};
    *reinterpret_cast<f32x4*>(trans_out + (size_t)slot*4) = t;
  }

  // m output (coalesced, CSR slot order)
  int el = lane >> 2, q = lane & 3;
  size_t mrow = (size_t)(blockIdx.x*64 + wt + el);
  #pragma unroll
  for (int it = 0; it < 2; ++it){
    int k = it*32 + q*8;
    uint4 v = *reinterpret_cast<const uint4*>(&XM[(wt + el)*88 + k]);
    *reinterpret_cast<uint4*>(m_out + mrow*HD + k) = v;
  }
}

// ---------------- aggregation: streaming segmented sum ----------------
__global__ __launch_bounds__(256) void k_agg(const ushort* __restrict__ m,
    const float* __restrict__ trans, const int* __restrict__ start,
    ushort* __restrict__ aggb, float* __restrict__ accv){
  int wave = threadIdx.x >> 6, lane = threadIdx.x & 63;
  int node = blockIdx.x*4 + wave;
  if (node >= NN) return;
  int s0 = start[node], s1 = start[node+1];
  int sub = lane >> 4, cg = lane & 15;

  float a0=0.f, a1=0.f, a2=0.f, a3=0.f;
  for (int t = s0 + sub; t < s1; t += 4){
    ushort4 v = *reinterpret_cast<const ushort4*>(m + (size_t)t*HD + cg*4);
    a0 += b2f(v.x); a1 += b2f(v.y); a2 += b2f(v.z); a3 += b2f(v.w);
  }
  #pragma unroll
  for (int off = 16; off < 64; off <<= 1){
    a0 += __shfl_xor(a0, off);
    a1 += __shfl_xor(a1, off);
    a2 += __shfl_xor(a2, off);
    a3 += __shfl_xor(a3, off);
  }
  if (lane < 16){
    ushort4 o;
    o.x = f2b(a0); o.y = f2b(a1); o.z = f2b(a2); o.w = f2b(a3);
    *reinterpret_cast<ushort4*>(aggb + (size_t)node*HD + cg*4) = o;
  }

  float tx=0.f, ty=0.f, tz=0.f;
  for (int t = s0 + lane; t < s1; t += 64){
    const float* tr = trans + (size_t)t*4;
    tx += tr[0]; ty += tr[1]; tz += tr[2];
  }
  #pragma unroll
  for (int off = 1; off < 64; off <<= 1){
    tx += __shfl_xor(tx, off);
    ty += __shfl_xor(ty, off);
    tz += __shfl_xor(tz, off);
  }
  if (lane == 0){
    float inv = 1.0f / fmaxf((float)(s1 - s0), 1.0f);
    accv[node*4+0] = tx * inv;
    accv[node*4+1] = ty * inv;
    accv[node*4+2] = tz * inv;
  }
}

// ---------------- node MFMA kernel (+fused vel/coord update) ----------------
__global__ __launch_bounds__(256) void k_node(
    const ushort* __restrict__ hb, const ushort* __restrict__ aggb, const float* __restrict__ h_in,
    const ushort* __restrict__ nW1p, const ushort* __restrict__ nW2p, const ushort* __restrict__ vW1p,
    const float* __restrict__ nb1, const float* __restrict__ nb2,
    const float* __restrict__ vb1, const float* __restrict__ vW2, const float* __restrict__ vb2,
    const float* __restrict__ accv, const float* __restrict__ vel_in, const float* __restrict__ coord_in,
    const float* __restrict__ speed0,
    float* __restrict__ h_out, ushort* __restrict__ hb_out,
    float* __restrict__ vel_out, float* __restrict__ coord_out)
{
  __shared__ __align__(16) ushort HID[64*88];
  __shared__ float VS[64];
  const int tid = threadIdx.x;
  const int wave = tid >> 6, lane = tid & 63;
  const int c = lane & 15, g = lane >> 4;
  const int wt = wave * 16;
  const int nbase = blockIdx.x * 64;
  int nA = nbase + wt + c;
  int nAc = (nA < NN) ? nA : (NN-1);

  short8 af[4];
  af[0] = *reinterpret_cast<const short8*>(hb   + (size_t)nAc*HD + g*8);
  af[1] = *reinterpret_cast<const short8*>(hb   + (size_t)nAc*HD + 32 + g*8);
  af[2] = *reinterpret_cast<const short8*>(aggb + (size_t)nAc*HD + g*8);
  af[3] = *reinterpret_cast<const short8*>(aggb + (size_t)nAc*HD + 32 + g*8);
  const short8* N1f = reinterpret_cast<const short8*>(nW1p);
  const short8* N2f = reinterpret_cast<const short8*>(nW2p);
  const short8* V1f = reinterpret_cast<const short8*>(vW1p);

  f32x4 acc[4];
  #pragma unroll
  for (int ct = 0; ct < 4; ++ct){
    float bb = nb1[ct*16 + c];
    acc[ct] = (f32x4){bb,bb,bb,bb};
  }
  #pragma unroll
  for (int kt = 0; kt < 4; ++kt){
    #pragma unroll
    for (int ct = 0; ct < 4; ++ct){
      acc[ct] = __builtin_amdgcn_mfma_f32_16x16x32_bf16(af[kt], N1f[(kt*4+ct)*64 + lane], acc[ct], 0,0,0);
    }
  }
  #pragma unroll
  for (int ct = 0; ct < 4; ++ct){
    int col = ct*16 + c;
    #pragma unroll
    for (int r = 0; r < 4; ++r){
      HID[(wt + g*4 + r)*88 + col] = f2b(silu_f(acc[ct][r]));
    }
  }

  // v MLP (uses h only)
  f32x4 av[4];
  #pragma unroll
  for (int ct = 0; ct < 4; ++ct){
    float bb = vb1[ct*16 + c];
    av[ct] = (f32x4){bb,bb,bb,bb};
  }
  #pragma unroll
  for (int kt = 0; kt < 2; ++kt){
    #pragma unroll
    for (int ct = 0; ct < 4; ++ct){
      av[ct] = __builtin_amdgcn_mfma_f32_16x16x32_bf16(af[kt], V1f[(kt*4+ct)*64 + lane], av[ct], 0,0,0);
    }
  }
  float pw[4] = {0.f,0.f,0.f,0.f};
  #pragma unroll
  for (int ct = 0; ct < 4; ++ct){
    int col = ct*16 + c;
    float vw = vW2[col];
    #pragma unroll
    for (int r = 0; r < 4; ++r) pw[r] += silu_f(av[ct][r]) * vw;
  }
  #pragma unroll
  for (int off = 1; off < 16; off <<= 1){
    #pragma unroll
    for (int r = 0; r < 4; ++r) pw[r] += __shfl_xor(pw[r], off, 16);
  }
  if (c == 0){
    float vbias = vb2[0];
    #pragma unroll
    for (int r = 0; r < 4; ++r) VS[wt + g*4 + r] = pw[r] + vbias;
  }

  // node MLP second layer (reads HID written by this wave only)
  short8 h0 = *reinterpret_cast<const short8*>(&HID[(wt + c)*88 + g*8]);
  short8 h1 = *reinterpret_cast<const short8*>(&HID[(wt + c)*88 + 32 + g*8]);
  f32x4 a2[4];
  #pragma unroll
  for (int ct = 0; ct < 4; ++ct){
    float bb = nb2[ct*16 + c];
    a2[ct] = (f32x4){bb,bb,bb,bb};
  }
  #pragma unroll
  for (int ct = 0; ct < 4; ++ct)
    a2[ct] = __builtin_amdgcn_mfma_f32_16x16x32_bf16(h0, N2f[(0*4+ct)*64 + lane], a2[ct], 0,0,0);
  #pragma unroll
  for (int ct = 0; ct < 4; ++ct)
    a2[ct] = __builtin_amdgcn_mfma_f32_16x16x32_bf16(h1, N2f[(1*4+ct)*64 + lane], a2[ct], 0,0,0);
  #pragma unroll
  for (int ct = 0; ct < 4; ++ct){
    int col = ct*16 + c;
    #pragma unroll
    for (int r = 0; r < 4; ++r){
      int n = nbase + wt + g*4 + r;
      if (n < NN){
        size_t off = (size_t)n*HD + col;
        float v = 2.0f*h_in[off] + a2[ct][r];
        h_out[off] = v;
        hb_out[off] = f2b(v);
      }
    }
  }

  // fused vel/coord update (needs VS across waves)
  __syncthreads();
  if (tid < 64){
    int n = nbase + tid;
    if (n < NN){
      float vsn = VS[tid];
      float ax = accv[n*4+0], ay = accv[n*4+1], az = accv[n*4+2];
      float v0 = vsn*vel_in[n*3+0] + ax*(1.0f/7.0f);
      float v1 = vsn*vel_in[n*3+1] + ay*(1.0f/7.0f);
      float v2 = vsn*vel_in[n*3+2] + az*(1.0f/7.0f);
      float s = speed0[n] / (sqrtf(v0*v0 + v1*v1 + v2*v2) + 1e-8f);
      v0 *= s; v1 *= s; v2 *= s;
      vel_out[n*3+0] = v0; vel_out[n*3+1] = v1; vel_out[n*3+2] = v2;
      coord_out[n*3+0] = coord_in[n*3+0] + v0*(1.0f/7.0f);
      coord_out[n*3+1] = coord_in[n*3+1] + v1*(1.0f/7.0f);
      coord_out[n*3+2] = coord_in[n*3+2] + v2*(1.0f/7.0f);
    }
  }
}

// ---------------- launcher ----------------
extern "C" void kernel_launch(void* const* d_in, const int* in_sizes, int n_in,
                              void* d_out, int out_size, void* d_ws, size_t ws_size,
                              hipStream_t stream)
{
  const float* his  = (const float*)d_in[0];
  const float* loc  = (const float*)d_in[1];
  const int*   edges= (const int*)d_in[2];
  const float* vel0 = (const float*)d_in[3];
  const float* eatt = (const float*)d_in[4];
  const float* embW = (const float*)d_in[5];
  const float* embB = (const float*)d_in[6];
  const float* eW1  = (const float*)d_in[7];
  const float* eB1  = (const float*)d_in[8];
  const float* eW2  = (const float*)d_in[9];
  const float* eB2  = (const float*)d_in[10];
  const float* cW1  = (const float*)d_in[11];
  const float* cB1  = (const float*)d_in[12];
  const float* cW2  = (const float*)d_in[13];
  const float* vW1  = (const float*)d_in[14];
  const float* vB1  = (const float*)d_in[15];
  const float* vW2  = (const float*)d_in[16];
  const float* vB2  = (const float*)d_in[17];
  const float* nW1  = (const float*)d_in[18];
  const float* nB1  = (const float*)d_in[19];
  const float* nW2  = (const float*)d_in[20];
  const float* nB2  = (const float*)d_in[21];
  const int* erow = edges;
  const int* ecol = edges + EE;

  char* ws = (char*)d_ws;
  size_t off = 0;
  auto alloc = [&](size_t bytes)->char*{
    char* p = ws + off;
    off = (off + bytes + 255) & ~(size_t)255;
    return p;
  };
  ushort* hb     = (ushort*)alloc((size_t)NN*HD*2);
  ushort* aggb   = (ushort*)alloc((size_t)NN*HD*2);
  int*    counts = (int*)   alloc((size_t)NN*4);
  int*    cursor = (int*)   alloc((size_t)NN*4);
  int*    startp = (int*)   alloc((size_t)(NN+1)*4);
  float*  coordw = (float*) alloc((size_t)NN*3*4);
  float*  velw   = (float*) alloc((size_t)NN*3*4);
  float*  speed0 = (float*) alloc((size_t)NN*4);
  float*  accv   = (float*) alloc((size_t)NN*4*4);
  ushort* W1p    = (ushort*)alloc(5*2048*2);
  ushort* W2p    = (ushort*)alloc(2*2048*2);
  ushort* cW1p   = (ushort*)alloc(2*2048*2);
  ushort* nW1p   = (ushort*)alloc(4*2048*2);
  ushort* nW2p   = (ushort*)alloc(2*2048*2);
  ushort* vW1p   = (ushort*)alloc(2*2048*2);
  int4*   erec   = (int4*)  alloc((size_t)EE*16);
  float*  trans  = (float*) alloc((size_t)EE*16);
  ushort* mbuf   = (ushort*)alloc((size_t)EE*HD*2);

  float* xout = (float*)d_out;                    // [N,3]
  float* hout = (float*)d_out + (size_t)NN*3;     // [N,64] — doubles as fp32 h buffer
  float* vout = (float*)d_out + (size_t)NN*3 + (size_t)NN*HD; // [N,3]

  hipMemsetAsync(counts, 0, (size_t)NN*4, stream);
  k_init<<<196,256,0,stream>>>(loc, vel0, coordw, velw, speed0);
  k_count<<<3125,256,0,stream>>>(erow, counts);
  k_scan<<<1,1024,0,stream>>>(counts, startp, cursor);
  k_fill<<<3125,256,0,stream>>>(erow, ecol, eatt, cursor, erec);
  k_pack<<<40,256,0,stream>>>(eW1, W1p, 131, 5);
  k_pack<<<16,256,0,stream>>>(eW2, W2p, 64, 2);
  k_pack<<<16,256,0,stream>>>(cW1, cW1p, 64, 2);
  k_pack<<<32,256,0,stream>>>(nW1, nW1p, 128, 4);
  k_pack<<<16,256,0,stream>>>(nW2, nW2p, 64, 2);
  k_pack<<<16,256,0,stream>>>(vW1, vW1p, 64, 2);
  k_embed<<<12500,256,0,stream>>>(his, embW, embB, hout, hb);

  for (int L = 0; L < 4; ++L){
    k_edge<<<12500,256,0,stream>>>(hb, coordw, erec,
        W1p, W2p, cW1p, eB1, eB2, cB1, cW2, mbuf, trans);
    k_agg<<<12500,256,0,stream>>>(mbuf, trans, startp, aggb, accv);
    float* v_o = (L == 3) ? vout : velw;
    float* c_o = (L == 3) ? xout : coordw;
    k_node<<<782,256,0,stream>>>(hb, aggb, hout, nW1p, nW2p, vW1p,
        nB1, nB2, vB1, vW2, vB2, accv, velw, coordw, speed0,
        hout, hb, v_o, c_o);
  }
}

// Round 4
// 625.994 us; speedup vs baseline: 1.7152x; 1.2762x over previous
//
#include <hip/hip_runtime.h>
#include <hip/hip_bf16.h>
#include <stdint.h>

#define NN 50000
#define EE 800000
#define HD 64
#define AGS 72   // aggf row stride: 64 feats + 3 trans + pad

typedef short short8 __attribute__((ext_vector_type(8)));
typedef float f32x4 __attribute__((ext_vector_type(4)));

__device__ __forceinline__ float b2f(ushort u){ return __uint_as_float(((uint32_t)u)<<16); }
__device__ __forceinline__ ushort f2b(float f){
  uint32_t u = __float_as_uint(f);
  u += 0x7fffu + ((u>>16)&1u);
  return (ushort)(u>>16);
}
__device__ __forceinline__ float silu_f(float x){
  return x * __builtin_amdgcn_rcpf(1.0f + __expf(-x));
}

// ---------------- prep kernels ----------------

__global__ __launch_bounds__(256) void k_init(const float* __restrict__ loc,
    const float* __restrict__ vel0, float* __restrict__ coordw,
    float* __restrict__ velw, float* __restrict__ speed0){
  int n = blockIdx.x*256 + threadIdx.x;
  if (n >= NN) return;
  float vx = vel0[n*3+0], vy = vel0[n*3+1], vz = vel0[n*3+2];
  speed0[n] = sqrtf(vx*vx + vy*vy + vz*vz);
  velw[n*3+0]=vx; velw[n*3+1]=vy; velw[n*3+2]=vz;
  coordw[n*3+0]=loc[n*3+0]; coordw[n*3+1]=loc[n*3+1]; coordw[n*3+2]=loc[n*3+2];
}

__global__ __launch_bounds__(256) void k_count(const int* __restrict__ erow, int* __restrict__ counts){
  int e = blockIdx.x*256 + threadIdx.x;
  if (e < EE) atomicAdd(&counts[erow[e]], 1);
}

__global__ __launch_bounds__(256) void k_bsum(const int* __restrict__ counts, int* __restrict__ bsum){
  __shared__ int sm[4];
  int tid = threadIdx.x;
  int i = blockIdx.x*256 + tid;
  int v = (i < NN) ? counts[i] : 0;
  #pragma unroll
  for (int off = 1; off < 64; off <<= 1) v += __shfl_xor(v, off);
  if ((tid & 63) == 0) sm[tid >> 6] = v;
  __syncthreads();
  if (tid == 0) bsum[blockIdx.x] = sm[0] + sm[1] + sm[2] + sm[3];
}

__global__ __launch_bounds__(256) void k_bscan(const int* __restrict__ bsum, int* __restrict__ bbase){
  __shared__ int sm[256];
  int tid = threadIdx.x;
  int v = (tid < 196) ? bsum[tid] : 0;
  sm[tid] = v;
  __syncthreads();
  #pragma unroll
  for (int off = 1; off < 256; off <<= 1){
    int t = (tid >= off) ? sm[tid - off] : 0;
    __syncthreads();
    sm[tid] += t;
    __syncthreads();
  }
  if (tid < 196) bbase[tid] = sm[tid] - v;   // exclusive
}

__global__ __launch_bounds__(256) void k_scatter(const int* __restrict__ counts,
    const int* __restrict__ bbase, int* __restrict__ cursor){
  __shared__ int sm[256];
  int tid = threadIdx.x;
  int i = blockIdx.x*256 + tid;
  int v = (i < NN) ? counts[i] : 0;
  sm[tid] = v;
  __syncthreads();
  #pragma unroll
  for (int off = 1; off < 256; off <<= 1){
    int t = (tid >= off) ? sm[tid - off] : 0;
    __syncthreads();
    sm[tid] += t;
    __syncthreads();
  }
  if (i < NN) cursor[i] = bbase[blockIdx.x] + sm[tid] - v;
}

// build CSR-sorted edge records {row, col, ea0, ea1}
__global__ __launch_bounds__(256) void k_fill(const int* __restrict__ erow,
    const int* __restrict__ ecol, const float* __restrict__ eattr,
    int* __restrict__ cursor, int4* __restrict__ erec){
  int e = blockIdx.x*256 + threadIdx.x;
  if (e < EE){
    int r = erow[e];
    int pos = atomicAdd(&cursor[r], 1);
    int4 rec;
    rec.x = r;
    rec.y = ecol[e];
    rec.z = __float_as_int(eattr[(size_t)e*2 + 0]);
    rec.w = __float_as_int(eattr[(size_t)e*2 + 1]);
    erec[pos] = rec;
  }
}

// pack weight [Ksrc,64] into MFMA B-frag order: ((kt*4+ct)*64+lane)*8+i
__global__ __launch_bounds__(256) void k_pack(const float* __restrict__ src,
    ushort* __restrict__ dst, int Ksrc, int ktTotal){
  int idx = blockIdx.x*256 + threadIdx.x;
  if (idx >= ktTotal*2048) return;
  int i = idx & 7;
  int lane = (idx >> 3) & 63;
  int ctkt = idx >> 9;
  int ct = ctkt & 3, kt = ctkt >> 2;
  int k = kt*32 + (lane>>4)*8 + i;
  int col = ct*16 + (lane & 15);
  float v = (k < Ksrc) ? src[k*64 + col] : 0.0f;
  dst[idx] = f2b(v);
}

__global__ __launch_bounds__(256) void k_embed(const float* __restrict__ his,
    const float* __restrict__ embW, const float* __restrict__ embB,
    float* __restrict__ h, ushort* __restrict__ hb){
  int idx = blockIdx.x*256 + threadIdx.x;
  if (idx >= NN*HD) return;
  int n = idx >> 6, j = idx & 63;
  float s = embB[j];
  #pragma unroll
  for (int k = 0; k < 8; ++k) s += his[n*8 + k] * embW[k*64 + j];
  h[idx] = s;
  hb[idx] = f2b(s);
}

// ---------------- edge MFMA kernel (fused aggregation, round-2 transpose) ----------------
__global__ __launch_bounds__(256) void k_edge(
    const ushort* __restrict__ hb, const float* __restrict__ coord,
    const int4* __restrict__ erec,
    const ushort* __restrict__ W1p, const ushort* __restrict__ W2p, const ushort* __restrict__ cW1p,
    const float* __restrict__ b1, const float* __restrict__ b2,
    const float* __restrict__ cb1, const float* __restrict__ cw2,
    float* __restrict__ aggf)
{
  __shared__ __align__(16) ushort XM[64*88];   // X1, then m (aliased; wave-private rows)
  __shared__ float TRL[64*4];
  __shared__ float WL[64];
  const int tid = threadIdx.x;
  const int wave = tid >> 6, lane = tid & 63;
  const int c = lane & 15, g = lane >> 4;
  const int wt = wave * 16;
  const int slot = blockIdx.x*64 + wt + c;

  int4 er = erec[slot];
  const int rA = er.x, cA = er.y;

  short8 af[5];
  af[0] = *reinterpret_cast<const short8*>(hb + (size_t)rA*HD + g*8);
  af[1] = *reinterpret_cast<const short8*>(hb + (size_t)rA*HD + 32 + g*8);
  af[2] = *reinterpret_cast<const short8*>(hb + (size_t)cA*HD + g*8);
  af[3] = *reinterpret_cast<const short8*>(hb + (size_t)cA*HD + 32 + g*8);
  float dx = coord[rA*3+0] - coord[cA*3+0];
  float dy = coord[rA*3+1] - coord[cA*3+1];
  float dz = coord[rA*3+2] - coord[cA*3+2];
  float radial = dx*dx + dy*dy + dz*dz;
  short8 a4 = {0,0,0,0,0,0,0,0};
  if (g == 0){
    a4[0] = (short)f2b(radial);
    a4[1] = (short)f2b(__int_as_float(er.z));
    a4[2] = (short)f2b(__int_as_float(er.w));
  }
  af[4] = a4;

  const short8* W1f = reinterpret_cast<const short8*>(W1p);
  const short8* W2f = reinterpret_cast<const short8*>(W2p);
  const short8* C1f = reinterpret_cast<const short8*>(cW1p);

  // GEMM1: X1 = silu(e_in @ W1 + b1)   (bias folded into acc init)
  f32x4 acc[4];
  #pragma unroll
  for (int ct = 0; ct < 4; ++ct){
    float bb = b1[ct*16 + c];
    acc[ct] = (f32x4){bb,bb,bb,bb};
  }
  #pragma unroll
  for (int kt = 0; kt < 5; ++kt){
    #pragma unroll
    for (int ct = 0; ct < 4; ++ct){
      acc[ct] = __builtin_amdgcn_mfma_f32_16x16x32_bf16(af[kt], W1f[(kt*4+ct)*64 + lane], acc[ct], 0,0,0);
    }
  }
  #pragma unroll
  for (int ct = 0; ct < 4; ++ct){
    int col = ct*16 + c;
    #pragma unroll
    for (int r = 0; r < 4; ++r){
      XM[(wt + g*4 + r)*88 + col] = f2b(silu_f(acc[ct][r]));
    }
  }
  // in-wave transpose read (DS ops are in-order per wave; wave-private rows)
  short8 xa0 = *reinterpret_cast<const short8*>(&XM[(wt + c)*88 + g*8]);
  short8 xa1 = *reinterpret_cast<const short8*>(&XM[(wt + c)*88 + 32 + g*8]);

  // GEMM2: m = silu(X1 @ W2 + b2)
  f32x4 acc2[4];
  #pragma unroll
  for (int ct = 0; ct < 4; ++ct){
    float bb = b2[ct*16 + c];
    acc2[ct] = (f32x4){bb,bb,bb,bb};
  }
  #pragma unroll
  for (int ct = 0; ct < 4; ++ct)
    acc2[ct] = __builtin_amdgcn_mfma_f32_16x16x32_bf16(xa0, W2f[(0*4+ct)*64 + lane], acc2[ct], 0,0,0);
  #pragma unroll
  for (int ct = 0; ct < 4; ++ct)
    acc2[ct] = __builtin_amdgcn_mfma_f32_16x16x32_bf16(xa1, W2f[(1*4+ct)*64 + lane], acc2[ct], 0,0,0);
  #pragma unroll
  for (int ct = 0; ct < 4; ++ct){
    int col = ct*16 + c;
    #pragma unroll
    for (int r = 0; r < 4; ++r){
      XM[(wt + g*4 + r)*88 + col] = f2b(silu_f(acc2[ct][r]));
    }
  }
  short8 ma0 = *reinterpret_cast<const short8*>(&XM[(wt + c)*88 + g*8]);
  short8 ma1 = *reinterpret_cast<const short8*>(&XM[(wt + c)*88 + 32 + g*8]);

  // GEMM3: X3 = silu(m @ cW1 + cb1); w = X3 @ cW2
  f32x4 acc3[4];
  #pragma unroll
  for (int ct = 0; ct < 4; ++ct){
    float bb = cb1[ct*16 + c];
    acc3[ct] = (f32x4){bb,bb,bb,bb};
  }
  #pragma unroll
  for (int ct = 0; ct < 4; ++ct)
    acc3[ct] = __builtin_amdgcn_mfma_f32_16x16x32_bf16(ma0, C1f[(0*4+ct)*64 + lane], acc3[ct], 0,0,0);
  #pragma unroll
  for (int ct = 0; ct < 4; ++ct)
    acc3[ct] = __builtin_amdgcn_mfma_f32_16x16x32_bf16(ma1, C1f[(1*4+ct)*64 + lane], acc3[ct], 0,0,0);

  float pw[4] = {0.f,0.f,0.f,0.f};
  #pragma unroll
  for (int ct = 0; ct < 4; ++ct){
    float cw = cw2[ct*16 + c];
    #pragma unroll
    for (int r = 0; r < 4; ++r) pw[r] += silu_f(acc3[ct][r]) * cw;
  }
  #pragma unroll
  for (int off = 1; off < 16; off <<= 1){
    #pragma unroll
    for (int r = 0; r < 4; ++r) pw[r] += __shfl_xor(pw[r], off, 16);
  }
  if (c == 0){
    #pragma unroll
    for (int r = 0; r < 4; ++r) WL[wt + g*4 + r] = pw[r];
  }
  float w = WL[wt + c];
  if (g == 0){
    TRL[(wt + c)*4 + 0] = dx*w;
    TRL[(wt + c)*4 + 1] = dy*w;
    TRL[(wt + c)*4 + 2] = dz*w;
  }

  // per-wave segmented sum over its 16 CSR-sorted edges -> atomic flush
  float sum = 0.f, ts = 0.f;
  int rcur = __shfl(rA, 0);
  #pragma unroll
  for (int i = 0; i < 16; ++i){
    sum += b2f(XM[(wt + i)*88 + lane]);
    if (lane < 3) ts += TRL[(wt + i)*4 + lane];
    int rnext = (i < 15) ? __shfl(rA, i+1) : -1;
    if (rnext != rcur){
      atomicAdd(&aggf[(size_t)rcur*AGS + lane], sum);
      if (lane < 3) atomicAdd(&aggf[(size_t)rcur*AGS + 64 + lane], ts);
      sum = 0.f; ts = 0.f; rcur = rnext;
    }
  }
}

// ---------------- node MFMA kernel (+fused vel/coord update) ----------------
__global__ __launch_bounds__(256) void k_node(
    const ushort* __restrict__ hb, const float* __restrict__ aggf, const float* __restrict__ h_in,
    const ushort* __restrict__ nW1p, const ushort* __restrict__ nW2p, const ushort* __restrict__ vW1p,
    const float* __restrict__ nb1, const float* __restrict__ nb2,
    const float* __restrict__ vb1, const float* __restrict__ vW2, const float* __restrict__ vb2,
    const int* __restrict__ counts, const float* __restrict__ vel_in, const float* __restrict__ coord_in,
    const float* __restrict__ speed0,
    float* __restrict__ h_out, ushort* __restrict__ hb_out,
    float* __restrict__ vel_out, float* __restrict__ coord_out)
{
  __shared__ __align__(16) ushort HID[64*88];
  __shared__ float VS[64];
  const int tid = threadIdx.x;
  const int wave = tid >> 6, lane = tid & 63;
  const int c = lane & 15, g = lane >> 4;
  const int wt = wave * 16;
  const int nbase = blockIdx.x * 64;
  int nA = nbase + wt + c;
  int nAc = (nA < NN) ? nA : (NN-1);

  short8 af[4];
  af[0] = *reinterpret_cast<const short8*>(hb + (size_t)nAc*HD + g*8);
  af[1] = *reinterpret_cast<const short8*>(hb + (size_t)nAc*HD + 32 + g*8);
  {
    const float* ag = aggf + (size_t)nAc*AGS;
    f32x4 q0 = *reinterpret_cast<const f32x4*>(ag + g*8);
    f32x4 q1 = *reinterpret_cast<const f32x4*>(ag + g*8 + 4);
    f32x4 q2 = *reinterpret_cast<const f32x4*>(ag + 32 + g*8);
    f32x4 q3 = *reinterpret_cast<const f32x4*>(ag + 32 + g*8 + 4);
    union FB { ushort u[8]; short8 s; };
    FB f2_, f3_;
    #pragma unroll
    for (int i = 0; i < 4; ++i){ f2_.u[i] = f2b(q0[i]); f2_.u[4+i] = f2b(q1[i]); }
    #pragma unroll
    for (int i = 0; i < 4; ++i){ f3_.u[i] = f2b(q2[i]); f3_.u[4+i] = f2b(q3[i]); }
    af[2] = f2_.s;
    af[3] = f3_.s;
  }
  const short8* N1f = reinterpret_cast<const short8*>(nW1p);
  const short8* N2f = reinterpret_cast<const short8*>(nW2p);
  const short8* V1f = reinterpret_cast<const short8*>(vW1p);

  f32x4 acc[4];
  #pragma unroll
  for (int ct = 0; ct < 4; ++ct){
    float bb = nb1[ct*16 + c];
    acc[ct] = (f32x4){bb,bb,bb,bb};
  }
  #pragma unroll
  for (int kt = 0; kt < 4; ++kt){
    #pragma unroll
    for (int ct = 0; ct < 4; ++ct){
      acc[ct] = __builtin_amdgcn_mfma_f32_16x16x32_bf16(af[kt], N1f[(kt*4+ct)*64 + lane], acc[ct], 0,0,0);
    }
  }
  #pragma unroll
  for (int ct = 0; ct < 4; ++ct){
    int col = ct*16 + c;
    #pragma unroll
    for (int r = 0; r < 4; ++r){
      HID[(wt + g*4 + r)*88 + col] = f2b(silu_f(acc[ct][r]));
    }
  }

  // v MLP (uses h only)
  f32x4 av[4];
  #pragma unroll
  for (int ct = 0; ct < 4; ++ct){
    float bb = vb1[ct*16 + c];
    av[ct] = (f32x4){bb,bb,bb,bb};
  }
  #pragma unroll
  for (int kt = 0; kt < 2; ++kt){
    #pragma unroll
    for (int ct = 0; ct < 4; ++ct){
      av[ct] = __builtin_amdgcn_mfma_f32_16x16x32_bf16(af[kt], V1f[(kt*4+ct)*64 + lane], av[ct], 0,0,0);
    }
  }
  float pw[4] = {0.f,0.f,0.f,0.f};
  #pragma unroll
  for (int ct = 0; ct < 4; ++ct){
    float vw = vW2[ct*16 + c];
    #pragma unroll
    for (int r = 0; r < 4; ++r) pw[r] += silu_f(av[ct][r]) * vw;
  }
  #pragma unroll
  for (int off = 1; off < 16; off <<= 1){
    #pragma unroll
    for (int r = 0; r < 4; ++r) pw[r] += __shfl_xor(pw[r], off, 16);
  }
  if (c == 0){
    float vbias = vb2[0];
    #pragma unroll
    for (int r = 0; r < 4; ++r) VS[wt + g*4 + r] = pw[r] + vbias;
  }

  // node MLP second layer (reads HID written by this wave only)
  short8 h0 = *reinterpret_cast<const short8*>(&HID[(wt + c)*88 + g*8]);
  short8 h1 = *reinterpret_cast<const short8*>(&HID[(wt + c)*88 + 32 + g*8]);
  f32x4 a2[4];
  #pragma unroll
  for (int ct = 0; ct < 4; ++ct){
    float bb = nb2[ct*16 + c];
    a2[ct] = (f32x4){bb,bb,bb,bb};
  }
  #pragma unroll
  for (int ct = 0; ct < 4; ++ct)
    a2[ct] = __builtin_amdgcn_mfma_f32_16x16x32_bf16(h0, N2f[(0*4+ct)*64 + lane], a2[ct], 0,0,0);
  #pragma unroll
  for (int ct = 0; ct < 4; ++ct)
    a2[ct] = __builtin_amdgcn_mfma_f32_16x16x32_bf16(h1, N2f[(1*4+ct)*64 + lane], a2[ct], 0,0,0);
  #pragma unroll
  for (int ct = 0; ct < 4; ++ct){
    int col = ct*16 + c;
    #pragma unroll
    for (int r = 0; r < 4; ++r){
      int n = nbase + wt + g*4 + r;
      if (n < NN){
        size_t off = (size_t)n*HD + col;
        float v = 2.0f*h_in[off] + a2[ct][r];
        h_out[off] = v;
        hb_out[off] = f2b(v);
      }
    }
  }

  // fused vel/coord update
  __syncthreads();
  if (tid < 64){
    int n = nbase + tid;
    if (n < NN){
      float vsn = VS[tid];
      float inv = 1.0f / fmaxf((float)counts[n], 1.0f);
      const float* ag = aggf + (size_t)n*AGS + 64;
      float ax = ag[0]*inv, ay = ag[1]*inv, az = ag[2]*inv;
      float v0 = vsn*vel_in[n*3+0] + ax*(1.0f/7.0f);
      float v1 = vsn*vel_in[n*3+1] + ay*(1.0f/7.0f);
      float v2 = vsn*vel_in[n*3+2] + az*(1.0f/7.0f);
      float s = speed0[n] / (sqrtf(v0*v0 + v1*v1 + v2*v2) + 1e-8f);
      v0 *= s; v1 *= s; v2 *= s;
      vel_out[n*3+0] = v0; vel_out[n*3+1] = v1; vel_out[n*3+2] = v2;
      coord_out[n*3+0] = coord_in[n*3+0] + v0*(1.0f/7.0f);
      coord_out[n*3+1] = coord_in[n*3+1] + v1*(1.0f/7.0f);
      coord_out[n*3+2] = coord_in[n*3+2] + v2*(1.0f/7.0f);
    }
  }
}

// ---------------- launcher ----------------
extern "C" void kernel_launch(void* const* d_in, const int* in_sizes, int n_in,
                              void* d_out, int out_size, void* d_ws, size_t ws_size,
                              hipStream_t stream)
{
  const float* his  = (const float*)d_in[0];
  const float* loc  = (const float*)d_in[1];
  const int*   edges= (const int*)d_in[2];
  const float* vel0 = (const float*)d_in[3];
  const float* eatt = (const float*)d_in[4];
  const float* embW = (const float*)d_in[5];
  const float* embB = (const float*)d_in[6];
  const float* eW1  = (const float*)d_in[7];
  const float* eB1  = (const float*)d_in[8];
  const float* eW2  = (const float*)d_in[9];
  const float* eB2  = (const float*)d_in[10];
  const float* cW1  = (const float*)d_in[11];
  const float* cB1  = (const float*)d_in[12];
  const float* cW2  = (const float*)d_in[13];
  const float* vW1  = (const float*)d_in[14];
  const float* vB1  = (const float*)d_in[15];
  const float* vW2  = (const float*)d_in[16];
  const float* vB2  = (const float*)d_in[17];
  const float* nW1  = (const float*)d_in[18];
  const float* nB1  = (const float*)d_in[19];
  const float* nW2  = (const float*)d_in[20];
  const float* nB2  = (const float*)d_in[21];
  const int* erow = edges;
  const int* ecol = edges + EE;

  char* ws = (char*)d_ws;
  size_t off = 0;
  auto alloc = [&](size_t bytes)->char*{
    char* p = ws + off;
    off = (off + bytes + 255) & ~(size_t)255;
    return p;
  };
  ushort* hb     = (ushort*)alloc((size_t)NN*HD*2);
  int*    counts = (int*)   alloc((size_t)NN*4);
  int*    cursor = (int*)   alloc((size_t)NN*4);
  int*    bsum   = (int*)   alloc(256*4);
  int*    bbase  = (int*)   alloc(256*4);
  float*  coordw = (float*) alloc((size_t)NN*3*4);
  float*  velw   = (float*) alloc((size_t)NN*3*4);
  float*  speed0 = (float*) alloc((size_t)NN*4);
  float*  aggf   = (float*) alloc((size_t)NN*AGS*4);
  ushort* W1p    = (ushort*)alloc(5*2048*2);
  ushort* W2p    = (ushort*)alloc(2*2048*2);
  ushort* cW1p   = (ushort*)alloc(2*2048*2);
  ushort* nW1p   = (ushort*)alloc(4*2048*2);
  ushort* nW2p   = (ushort*)alloc(2*2048*2);
  ushort* vW1p   = (ushort*)alloc(2*2048*2);
  int4*   erec   = (int4*)  alloc((size_t)EE*16);

  float* xout = (float*)d_out;                    // [N,3]
  float* hout = (float*)d_out + (size_t)NN*3;     // [N,64] — doubles as fp32 h buffer
  float* vout = (float*)d_out + (size_t)NN*3 + (size_t)NN*HD; // [N,3]

  hipMemsetAsync(counts, 0, (size_t)NN*4, stream);
  k_init<<<196,256,0,stream>>>(loc, vel0, coordw, velw, speed0);
  k_count<<<3125,256,0,stream>>>(erow, counts);
  k_bsum<<<196,256,0,stream>>>(counts, bsum);
  k_bscan<<<1,256,0,stream>>>(bsum, bbase);
  k_scatter<<<196,256,0,stream>>>(counts, bbase, cursor);
  k_fill<<<3125,256,0,stream>>>(erow, ecol, eatt, cursor, erec);
  k_pack<<<40,256,0,stream>>>(eW1, W1p, 131, 5);
  k_pack<<<16,256,0,stream>>>(eW2, W2p, 64, 2);
  k_pack<<<16,256,0,stream>>>(cW1, cW1p, 64, 2);
  k_pack<<<32,256,0,stream>>>(nW1, nW1p, 128, 4);
  k_pack<<<16,256,0,stream>>>(nW2, nW2p, 64, 2);
  k_pack<<<16,256,0,stream>>>(vW1, vW1p, 64, 2);
  k_embed<<<12500,256,0,stream>>>(his, embW, embB, hout, hb);

  for (int L = 0; L < 4; ++L){
    hipMemsetAsync(aggf, 0, (size_t)NN*AGS*4, stream);
    k_edge<<<12500,256,0,stream>>>(hb, coordw, erec,
        W1p, W2p, cW1p, eB1, eB2, cB1, cW2, aggf);
    float* v_o = (L == 3) ? vout : velw;
    float* c_o = (L == 3) ? xout : coordw;
    k_node<<<782,256,0,stream>>>(hb, aggf, hout, nW1p, nW2p, vW1p,
        nB1, nB2, vB1, vW2, vB2, counts, velw, coordw, speed0,
        hout, hb, v_o, c_o);
  }
}

// Round 5
// 596.943 us; speedup vs baseline: 1.7986x; 1.0487x over previous
//
#include <hip/hip_runtime.h>
#include <hip/hip_bf16.h>
#include <stdint.h>

#define NN 50000
#define EE 800000
#define HD 64
#define AGS 72   // aggf row stride: 64 feats + 3 trans + pad

typedef short short8 __attribute__((ext_vector_type(8)));
typedef float f32x4 __attribute__((ext_vector_type(4)));
typedef uint  uint2v __attribute__((ext_vector_type(2)));

__device__ __forceinline__ float b2f(ushort u){ return __uint_as_float(((uint32_t)u)<<16); }
__device__ __forceinline__ ushort f2b(float f){
  uint32_t u = __float_as_uint(f);
  u += 0x7fffu + ((u>>16)&1u);
  return (ushort)(u>>16);
}
// pack two f32 -> one u32 of 2 bf16 (lo = first arg), via HIP library intrinsic
__device__ __forceinline__ uint pk2(float lo, float hi){
  union { __hip_bfloat162 b; uint u; } x;
  x.b = __float22bfloat162_rn(make_float2(lo, hi));
  return x.u;
}
__device__ __forceinline__ float silu_f(float x){
  return x * __builtin_amdgcn_rcpf(1.0f + __expf(-x));
}

// ---------------- prep kernels ----------------

// merged: edge-count atomics + node init
__global__ __launch_bounds__(256) void k_count2(const int* __restrict__ erow,
    int* __restrict__ counts, const float* __restrict__ loc,
    const float* __restrict__ vel0, float* __restrict__ coordw,
    float* __restrict__ velw, float* __restrict__ speed0){
  int gid = blockIdx.x*256 + threadIdx.x;
  if (gid < EE) atomicAdd(&counts[erow[gid]], 1);
  if (gid < NN){
    float vx = vel0[gid*3+0], vy = vel0[gid*3+1], vz = vel0[gid*3+2];
    speed0[gid] = sqrtf(vx*vx + vy*vy + vz*vz);
    velw[gid*3+0]=vx; velw[gid*3+1]=vy; velw[gid*3+2]=vz;
    coordw[gid*3+0]=loc[gid*3+0]; coordw[gid*3+1]=loc[gid*3+1]; coordw[gid*3+2]=loc[gid*3+2];
  }
}

__global__ __launch_bounds__(256) void k_bsum(const int* __restrict__ counts, int* __restrict__ bsum){
  __shared__ int sm[4];
  int tid = threadIdx.x;
  int i = blockIdx.x*256 + tid;
  int v = (i < NN) ? counts[i] : 0;
  #pragma unroll
  for (int off = 1; off < 64; off <<= 1) v += __shfl_xor(v, off);
  if ((tid & 63) == 0) sm[tid >> 6] = v;
  __syncthreads();
  if (tid == 0) bsum[blockIdx.x] = sm[0] + sm[1] + sm[2] + sm[3];
}

__global__ __launch_bounds__(256) void k_bscan(const int* __restrict__ bsum, int* __restrict__ bbase){
  __shared__ int sm[256];
  int tid = threadIdx.x;
  int v = (tid < 196) ? bsum[tid] : 0;
  sm[tid] = v;
  __syncthreads();
  #pragma unroll
  for (int off = 1; off < 256; off <<= 1){
    int t = (tid >= off) ? sm[tid - off] : 0;
    __syncthreads();
    sm[tid] += t;
    __syncthreads();
  }
  if (tid < 196) bbase[tid] = sm[tid] - v;   // exclusive
}

__global__ __launch_bounds__(256) void k_scatter(const int* __restrict__ counts,
    const int* __restrict__ bbase, int* __restrict__ cursor){
  __shared__ int sm[256];
  int tid = threadIdx.x;
  int i = blockIdx.x*256 + tid;
  int v = (i < NN) ? counts[i] : 0;
  sm[tid] = v;
  __syncthreads();
  #pragma unroll
  for (int off = 1; off < 256; off <<= 1){
    int t = (tid >= off) ? sm[tid - off] : 0;
    __syncthreads();
    sm[tid] += t;
    __syncthreads();
  }
  if (i < NN) cursor[i] = bbase[blockIdx.x] + sm[tid] - v;
}

// build CSR-sorted edge records {row, col, ea0, ea1}
__global__ __launch_bounds__(256) void k_fill(const int* __restrict__ erow,
    const int* __restrict__ ecol, const float* __restrict__ eattr,
    int* __restrict__ cursor, int4* __restrict__ erec){
  int e = blockIdx.x*256 + threadIdx.x;
  if (e < EE){
    int r = erow[e];
    int pos = atomicAdd(&cursor[r], 1);
    int4 rec;
    rec.x = r;
    rec.y = ecol[e];
    rec.z = __float_as_int(eattr[(size_t)e*2 + 0]);
    rec.w = __float_as_int(eattr[(size_t)e*2 + 1]);
    erec[pos] = rec;
  }
}

// pack ALL weights [Ksrc,64] into MFMA frag order in one kernel.
// segments (x2048 elems): 0-4 eW1(K=131), 5-6 eW2, 7-8 cW1, 9-12 nW1(K=128), 13-14 nW2, 15-16 vW1
__global__ __launch_bounds__(256) void k_packall(const float* __restrict__ eW1,
    const float* __restrict__ eW2, const float* __restrict__ cW1,
    const float* __restrict__ nW1, const float* __restrict__ nW2,
    const float* __restrict__ vW1, ushort* __restrict__ dst){
  int idx = blockIdx.x*256 + threadIdx.x;
  if (idx >= 17*2048) return;
  int seg = idx >> 11;
  const float* src; int kt; int Ksrc;
  if      (seg < 5) { src = eW1; kt = seg;      Ksrc = 131; }
  else if (seg < 7) { src = eW2; kt = seg - 5;  Ksrc = 64;  }
  else if (seg < 9) { src = cW1; kt = seg - 7;  Ksrc = 64;  }
  else if (seg < 13){ src = nW1; kt = seg - 9;  Ksrc = 128; }
  else if (seg < 15){ src = nW2; kt = seg - 13; Ksrc = 64;  }
  else              { src = vW1; kt = seg - 15; Ksrc = 64;  }
  int within = idx & 2047;
  int i = within & 7;
  int lane = (within >> 3) & 63;
  int ct = (within >> 9) & 3;
  int k = kt*32 + (lane>>4)*8 + i;
  int col = ct*16 + (lane & 15);
  float v = (k < Ksrc) ? src[k*64 + col] : 0.0f;
  dst[idx] = f2b(v);
}

__global__ __launch_bounds__(256) void k_embed(const float* __restrict__ his,
    const float* __restrict__ embW, const float* __restrict__ embB,
    float* __restrict__ h, ushort* __restrict__ hb){
  int idx = blockIdx.x*256 + threadIdx.x;
  if (idx >= NN*HD) return;
  int n = idx >> 6, j = idx & 63;
  float s = embB[j];
  #pragma unroll
  for (int k = 0; k < 8; ++k) s += his[n*8 + k] * embW[k*64 + j];
  h[idx] = s;
  hb[idx] = f2b(s);
}

// ---------------- edge MFMA kernel: ALL-SWAPPED orientation ----------------
// Every GEMM computed as D = W^T · X^T (A = packed weight frags, B = edge-data frags).
// Lane (c,g): owns edge c of its wave tile; D lane(c,g) reg r = X[edge c][feature mt*16+g*4+r].
// LDS XMT: per-edge packed bf16, edge-major, stride 36 words; word w = feature pair (2w,2w+1).
__global__ __launch_bounds__(256) void k_edge(
    const ushort* __restrict__ hb, const float* __restrict__ coord,
    const int4* __restrict__ erec,
    const ushort* __restrict__ W1p, const ushort* __restrict__ W2p, const ushort* __restrict__ cW1p,
    const float* __restrict__ b1, const float* __restrict__ b2,
    const float* __restrict__ cb1, const float* __restrict__ cw2,
    float* __restrict__ aggf)
{
  __shared__ __align__(16) uint XMT[64*36];   // X1 then m (aliased; wave-private rows)
  __shared__ float TRL[64*4];
  const int tid = threadIdx.x;
  const int wave = tid >> 6, lane = tid & 63;
  const int c = lane & 15, g = lane >> 4;
  const int wt = wave * 16;
  const int slot = blockIdx.x*64 + wt + c;

  int4 er = erec[slot];
  const int rA = er.x, cA = er.y;

  // B-frags for GEMM1 (K=160): e_in^T[k][edge c]
  short8 af[5];
  af[0] = *reinterpret_cast<const short8*>(hb + (size_t)rA*HD + g*8);
  af[1] = *reinterpret_cast<const short8*>(hb + (size_t)rA*HD + 32 + g*8);
  af[2] = *reinterpret_cast<const short8*>(hb + (size_t)cA*HD + g*8);
  af[3] = *reinterpret_cast<const short8*>(hb + (size_t)cA*HD + 32 + g*8);
  float dx = coord[rA*3+0] - coord[cA*3+0];
  float dy = coord[rA*3+1] - coord[cA*3+1];
  float dz = coord[rA*3+2] - coord[cA*3+2];
  float radial = dx*dx + dy*dy + dz*dz;
  short8 a4 = {0,0,0,0,0,0,0,0};
  if (g == 0){
    a4[0] = (short)f2b(radial);
    a4[1] = (short)f2b(__int_as_float(er.z));
    a4[2] = (short)f2b(__int_as_float(er.w));
  }
  af[4] = a4;

  const short8* W1f = reinterpret_cast<const short8*>(W1p);
  const short8* W2f = reinterpret_cast<const short8*>(W2p);
  const short8* C1f = reinterpret_cast<const short8*>(cW1p);

  // GEMM1 swapped: D1 = W1^T e_in^T ; bias vec-loaded per (mt,g)
  f32x4 acc[4];
  #pragma unroll
  for (int mt = 0; mt < 4; ++mt)
    acc[mt] = *reinterpret_cast<const f32x4*>(b1 + mt*16 + g*4);
  #pragma unroll
  for (int kt = 0; kt < 5; ++kt){
    #pragma unroll
    for (int mt = 0; mt < 4; ++mt){
      acc[mt] = __builtin_amdgcn_mfma_f32_16x16x32_bf16(W1f[(kt*4+mt)*64 + lane], af[kt], acc[mt], 0,0,0);
    }
  }
  // silu -> pack pairs -> LDS (word = mt*8 + g*2 + p within row wt+c)
  const int wrow = (wt + c)*36;
  #pragma unroll
  for (int mt = 0; mt < 4; ++mt){
    uint u0 = pk2(silu_f(acc[mt][0]), silu_f(acc[mt][1]));
    uint u1 = pk2(silu_f(acc[mt][2]), silu_f(acc[mt][3]));
    *reinterpret_cast<uint2v*>(&XMT[wrow + mt*8 + g*2]) = (uint2v){u0, u1};
  }
  __builtin_amdgcn_sched_barrier(0);
  // B-frags for GEMM2: X1[c][g*8+i] = words wrow + g*4 (+16 for k>=32)
  short8 xb0 = *reinterpret_cast<const short8*>(&XMT[wrow + g*4]);
  short8 xb1 = *reinterpret_cast<const short8*>(&XMT[wrow + 16 + g*4]);

  // GEMM2 swapped: m^T
  f32x4 acc2[4];
  #pragma unroll
  for (int mt = 0; mt < 4; ++mt)
    acc2[mt] = *reinterpret_cast<const f32x4*>(b2 + mt*16 + g*4);
  #pragma unroll
  for (int mt = 0; mt < 4; ++mt)
    acc2[mt] = __builtin_amdgcn_mfma_f32_16x16x32_bf16(W2f[(0*4+mt)*64 + lane], xb0, acc2[mt], 0,0,0);
  #pragma unroll
  for (int mt = 0; mt < 4; ++mt)
    acc2[mt] = __builtin_amdgcn_mfma_f32_16x16x32_bf16(W2f[(1*4+mt)*64 + lane], xb1, acc2[mt], 0,0,0);
  // m: silu -> pack -> same LDS layout (overwrites X1; ordering safe via dataflow)
  #pragma unroll
  for (int mt = 0; mt < 4; ++mt){
    uint u0 = pk2(silu_f(acc2[mt][0]), silu_f(acc2[mt][1]));
    uint u1 = pk2(silu_f(acc2[mt][2]), silu_f(acc2[mt][3]));
    *reinterpret_cast<uint2v*>(&XMT[wrow + mt*8 + g*2]) = (uint2v){u0, u1};
  }
  __builtin_amdgcn_sched_barrier(0);
  short8 xc0 = *reinterpret_cast<const short8*>(&XMT[wrow + g*4]);
  short8 xc1 = *reinterpret_cast<const short8*>(&XMT[wrow + 16 + g*4]);

  // GEMM3 swapped: X3^T = cW1^T m^T
  f32x4 acc3[4];
  #pragma unroll
  for (int mt = 0; mt < 4; ++mt)
    acc3[mt] = *reinterpret_cast<const f32x4*>(cb1 + mt*16 + g*4);
  #pragma unroll
  for (int mt = 0; mt < 4; ++mt)
    acc3[mt] = __builtin_amdgcn_mfma_f32_16x16x32_bf16(C1f[(0*4+mt)*64 + lane], xc0, acc3[mt], 0,0,0);
  #pragma unroll
  for (int mt = 0; mt < 4; ++mt)
    acc3[mt] = __builtin_amdgcn_mfma_f32_16x16x32_bf16(C1f[(1*4+mt)*64 + lane], xc1, acc3[mt], 0,0,0);

  // w = sum_f silu(X3[c][f]) * cw2[f] : per-lane partial then 2-step cross-g reduce
  float pw = 0.0f;
  #pragma unroll
  for (int mt = 0; mt < 4; ++mt){
    f32x4 cw4 = *reinterpret_cast<const f32x4*>(cw2 + mt*16 + g*4);
    #pragma unroll
    for (int r = 0; r < 4; ++r) pw += silu_f(acc3[mt][r]) * cw4[r];
  }
  pw += __shfl_xor(pw, 16);
  pw += __shfl_xor(pw, 32);
  if (g == 0){
    TRL[(wt + c)*4 + 0] = dx*pw;
    TRL[(wt + c)*4 + 1] = dy*pw;
    TRL[(wt + c)*4 + 2] = dz*pw;
  }

  // per-wave segmented sum over 16 CSR-sorted edges -> atomic flush
  const ushort* mvals = reinterpret_cast<const ushort*>(XMT);
  float sum = 0.f, ts = 0.f;
  int rcur = __builtin_amdgcn_readlane(rA, 0);
  #pragma unroll
  for (int i = 0; i < 16; ++i){
    sum += b2f(mvals[(wt + i)*72 + lane]);
    if (lane < 3) ts += TRL[(wt + i)*4 + lane];
    int rnext = (i < 15) ? __builtin_amdgcn_readlane(rA, i+1) : -1;
    if (rnext != rcur){
      atomicAdd(&aggf[(size_t)rcur*AGS + lane], sum);
      if (lane < 3) atomicAdd(&aggf[(size_t)rcur*AGS + 64 + lane], ts);
      sum = 0.f; ts = 0.f; rcur = rnext;
    }
  }
}

// ---------------- node MFMA kernel (+fused vel/coord update, +aggf re-zero) ----------------
__global__ __launch_bounds__(256) void k_node(
    const ushort* __restrict__ hb, float* __restrict__ aggf, const float* __restrict__ h_in,
    const ushort* __restrict__ nW1p, const ushort* __restrict__ nW2p, const ushort* __restrict__ vW1p,
    const float* __restrict__ nb1, const float* __restrict__ nb2,
    const float* __restrict__ vb1, const float* __restrict__ vW2, const float* __restrict__ vb2,
    const int* __restrict__ counts, const float* __restrict__ vel_in, const float* __restrict__ coord_in,
    const float* __restrict__ speed0,
    float* __restrict__ h_out, ushort* __restrict__ hb_out,
    float* __restrict__ vel_out, float* __restrict__ coord_out)
{
  __shared__ __align__(16) ushort HID[64*88];
  __shared__ float VS[64];
  const int tid = threadIdx.x;
  const int wave = tid >> 6, lane = tid & 63;
  const int c = lane & 15, g = lane >> 4;
  const int wt = wave * 16;
  const int nbase = blockIdx.x * 64;
  int nA = nbase + wt + c;
  int nAc = (nA < NN) ? nA : (NN-1);

  short8 af[4];
  af[0] = *reinterpret_cast<const short8*>(hb + (size_t)nAc*HD + g*8);
  af[1] = *reinterpret_cast<const short8*>(hb + (size_t)nAc*HD + 32 + g*8);
  {
    const float* ag = aggf + (size_t)nAc*AGS;
    f32x4 q0 = *reinterpret_cast<const f32x4*>(ag + g*8);
    f32x4 q1 = *reinterpret_cast<const f32x4*>(ag + g*8 + 4);
    f32x4 q2 = *reinterpret_cast<const f32x4*>(ag + 32 + g*8);
    f32x4 q3 = *reinterpret_cast<const f32x4*>(ag + 32 + g*8 + 4);
    union FB { ushort u[8]; short8 s; };
    FB f2_, f3_;
    #pragma unroll
    for (int i = 0; i < 4; ++i){ f2_.u[i] = f2b(q0[i]); f2_.u[4+i] = f2b(q1[i]); }
    #pragma unroll
    for (int i = 0; i < 4; ++i){ f3_.u[i] = f2b(q2[i]); f3_.u[4+i] = f2b(q3[i]); }
    af[2] = f2_.s;
    af[3] = f3_.s;
  }
  const short8* N1f = reinterpret_cast<const short8*>(nW1p);
  const short8* N2f = reinterpret_cast<const short8*>(nW2p);
  const short8* V1f = reinterpret_cast<const short8*>(vW1p);

  f32x4 acc[4];
  #pragma unroll
  for (int ct = 0; ct < 4; ++ct){
    float bb = nb1[ct*16 + c];
    acc[ct] = (f32x4){bb,bb,bb,bb};
  }
  #pragma unroll
  for (int kt = 0; kt < 4; ++kt){
    #pragma unroll
    for (int ct = 0; ct < 4; ++ct){
      acc[ct] = __builtin_amdgcn_mfma_f32_16x16x32_bf16(af[kt], N1f[(kt*4+ct)*64 + lane], acc[ct], 0,0,0);
    }
  }
  #pragma unroll
  for (int ct = 0; ct < 4; ++ct){
    int col = ct*16 + c;
    #pragma unroll
    for (int r = 0; r < 4; ++r){
      HID[(wt + g*4 + r)*88 + col] = f2b(silu_f(acc[ct][r]));
    }
  }

  // v MLP (uses h only)
  f32x4 av[4];
  #pragma unroll
  for (int ct = 0; ct < 4; ++ct){
    float bb = vb1[ct*16 + c];
    av[ct] = (f32x4){bb,bb,bb,bb};
  }
  #pragma unroll
  for (int kt = 0; kt < 2; ++kt){
    #pragma unroll
    for (int ct = 0; ct < 4; ++ct){
      av[ct] = __builtin_amdgcn_mfma_f32_16x16x32_bf16(af[kt], V1f[(kt*4+ct)*64 + lane], av[ct], 0,0,0);
    }
  }
  float pw[4] = {0.f,0.f,0.f,0.f};
  #pragma unroll
  for (int ct = 0; ct < 4; ++ct){
    float vw = vW2[ct*16 + c];
    #pragma unroll
    for (int r = 0; r < 4; ++r) pw[r] += silu_f(av[ct][r]) * vw;
  }
  #pragma unroll
  for (int off = 1; off < 16; off <<= 1){
    #pragma unroll
    for (int r = 0; r < 4; ++r) pw[r] += __shfl_xor(pw[r], off, 16);
  }
  if (c == 0){
    float vbias = vb2[0];
    #pragma unroll
    for (int r = 0; r < 4; ++r) VS[wt + g*4 + r] = pw[r] + vbias;
  }

  // node MLP second layer (reads HID written by this wave only)
  short8 h0 = *reinterpret_cast<const short8*>(&HID[(wt + c)*88 + g*8]);
  short8 h1 = *reinterpret_cast<const short8*>(&HID[(wt + c)*88 + 32 + g*8]);
  f32x4 a2[4];
  #pragma unroll
  for (int ct = 0; ct < 4; ++ct){
    float bb = nb2[ct*16 + c];
    a2[ct] = (f32x4){bb,bb,bb,bb};
  }
  #pragma unroll
  for (int ct = 0; ct < 4; ++ct)
    a2[ct] = __builtin_amdgcn_mfma_f32_16x16x32_bf16(h0, N2f[(0*4+ct)*64 + lane], a2[ct], 0,0,0);
  #pragma unroll
  for (int ct = 0; ct < 4; ++ct)
    a2[ct] = __builtin_amdgcn_mfma_f32_16x16x32_bf16(h1, N2f[(1*4+ct)*64 + lane], a2[ct], 0,0,0);
  #pragma unroll
  for (int ct = 0; ct < 4; ++ct){
    int col = ct*16 + c;
    #pragma unroll
    for (int r = 0; r < 4; ++r){
      int n = nbase + wt + g*4 + r;
      if (n < NN){
        size_t off = (size_t)n*HD + col;
        float v = 2.0f*h_in[off] + a2[ct][r];
        h_out[off] = v;
        hb_out[off] = f2b(v);
      }
    }
  }

  // fused vel/coord update
  __syncthreads();
  if (tid < 64){
    int n = nbase + tid;
    if (n < NN){
      float vsn = VS[tid];
      float inv = 1.0f / fmaxf((float)counts[n], 1.0f);
      const float* ag = aggf + (size_t)n*AGS + 64;
      float ax = ag[0]*inv, ay = ag[1]*inv, az = ag[2]*inv;
      float v0 = vsn*vel_in[n*3+0] + ax*(1.0f/7.0f);
      float v1 = vsn*vel_in[n*3+1] + ay*(1.0f/7.0f);
      float v2 = vsn*vel_in[n*3+2] + az*(1.0f/7.0f);
      float s = speed0[n] / (sqrtf(v0*v0 + v1*v1 + v2*v2) + 1e-8f);
      v0 *= s; v1 *= s; v2 *= s;
      vel_out[n*3+0] = v0; vel_out[n*3+1] = v1; vel_out[n*3+2] = v2;
      coord_out[n*3+0] = coord_in[n*3+0] + v0*(1.0f/7.0f);
      coord_out[n*3+1] = coord_in[n*3+1] + v1*(1.0f/7.0f);
      coord_out[n*3+2] = coord_in[n*3+2] + v2*(1.0f/7.0f);
    }
  }

  // re-zero this block's aggf rows for the next layer (replaces per-layer memset)
  __syncthreads();
  int nvalid = NN - nbase; if (nvalid > 64) nvalid = 64;
  float* zb = aggf + (size_t)nbase*AGS;
  for (int idx2 = tid; idx2 < nvalid*AGS; idx2 += 256) zb[idx2] = 0.0f;
}

// ---------------- launcher ----------------
extern "C" void kernel_launch(void* const* d_in, const int* in_sizes, int n_in,
                              void* d_out, int out_size, void* d_ws, size_t ws_size,
                              hipStream_t stream)
{
  const float* his  = (const float*)d_in[0];
  const float* loc  = (const float*)d_in[1];
  const int*   edges= (const int*)d_in[2];
  const float* vel0 = (const float*)d_in[3];
  const float* eatt = (const float*)d_in[4];
  const float* embW = (const float*)d_in[5];
  const float* embB = (const float*)d_in[6];
  const float* eW1  = (const float*)d_in[7];
  const float* eB1  = (const float*)d_in[8];
  const float* eW2  = (const float*)d_in[9];
  const float* eB2  = (const float*)d_in[10];
  const float* cW1  = (const float*)d_in[11];
  const float* cB1  = (const float*)d_in[12];
  const float* cW2  = (const float*)d_in[13];
  const float* vW1  = (const float*)d_in[14];
  const float* vB1  = (const float*)d_in[15];
  const float* vW2  = (const float*)d_in[16];
  const float* vB2  = (const float*)d_in[17];
  const float* nW1  = (const float*)d_in[18];
  const float* nB1  = (const float*)d_in[19];
  const float* nW2  = (const float*)d_in[20];
  const float* nB2  = (const float*)d_in[21];
  const int* erow = edges;
  const int* ecol = edges + EE;

  char* ws = (char*)d_ws;
  size_t off = 0;
  auto alloc = [&](size_t bytes)->char*{
    char* p = ws + off;
    off = (off + bytes + 255) & ~(size_t)255;
    return p;
  };
  ushort* hb     = (ushort*)alloc((size_t)NN*HD*2);
  int*    counts = (int*)   alloc((size_t)NN*4);
  int*    cursor = (int*)   alloc((size_t)NN*4);
  int*    bsum   = (int*)   alloc(256*4);
  int*    bbase  = (int*)   alloc(256*4);
  float*  coordw = (float*) alloc((size_t)NN*3*4);
  float*  velw   = (float*) alloc((size_t)NN*3*4);
  float*  speed0 = (float*) alloc((size_t)NN*4);
  float*  aggf   = (float*) alloc((size_t)NN*AGS*4);
  ushort* allp   = (ushort*)alloc(17*2048*2);
  int4*   erec   = (int4*)  alloc((size_t)EE*16);

  ushort* W1p  = allp;             // 5 kt
  ushort* W2p  = allp + 5*2048;    // 2 kt
  ushort* cW1p = allp + 7*2048;    // 2 kt
  ushort* nW1p = allp + 9*2048;    // 4 kt
  ushort* nW2p = allp + 13*2048;   // 2 kt
  ushort* vW1p = allp + 15*2048;   // 2 kt

  float* xout = (float*)d_out;                    // [N,3]
  float* hout = (float*)d_out + (size_t)NN*3;     // [N,64] — doubles as fp32 h buffer
  float* vout = (float*)d_out + (size_t)NN*3 + (size_t)NN*HD; // [N,3]

  hipMemsetAsync(counts, 0, (size_t)NN*4, stream);
  hipMemsetAsync(aggf, 0, (size_t)NN*AGS*4, stream);
  k_count2<<<3125,256,0,stream>>>(erow, counts, loc, vel0, coordw, velw, speed0);
  k_bsum<<<196,256,0,stream>>>(counts, bsum);
  k_bscan<<<1,256,0,stream>>>(bsum, bbase);
  k_scatter<<<196,256,0,stream>>>(counts, bbase, cursor);
  k_fill<<<3125,256,0,stream>>>(erow, ecol, eatt, cursor, erec);
  k_packall<<<136,256,0,stream>>>(eW1, eW2, cW1, nW1, nW2, vW1, allp);
  k_embed<<<12500,256,0,stream>>>(his, embW, embB, hout, hb);

  for (int L = 0; L < 4; ++L){
    k_edge<<<12500,256,0,stream>>>(hb, coordw, erec,
        W1p, W2p, cW1p, eB1, eB2, cB1, cW2, aggf);
    float* v_o = (L == 3) ? vout : velw;
    float* c_o = (L == 3) ? xout : coordw;
    k_node<<<782,256,0,stream>>>(hb, aggf, hout, nW1p, nW2p, vW1p,
        nB1, nB2, vB1, vW2, vB2, counts, velw, coordw, speed0,
        hout, hb, v_o, c_o);
  }
}

// Round 6
// 531.924 us; speedup vs baseline: 2.0185x; 1.1222x over previous
//
#include <hip/hip_runtime.h>
#include <hip/hip_bf16.h>
#include <stdint.h>

#define NN 50000
#define EE 800000
#define HD 64
#define AGS 72   // aggf row stride: 64 feats + 3 trans + pad

typedef short short8 __attribute__((ext_vector_type(8)));
typedef float f32x4  __attribute__((ext_vector_type(4)));
typedef float f32x16 __attribute__((ext_vector_type(16)));
typedef uint  uint2v __attribute__((ext_vector_type(2)));

__device__ __forceinline__ float b2f(ushort u){ return __uint_as_float(((uint32_t)u)<<16); }
__device__ __forceinline__ ushort f2b(float f){
  uint32_t u = __float_as_uint(f);
  u += 0x7fffu + ((u>>16)&1u);
  return (ushort)(u>>16);
}
__device__ __forceinline__ uint pk2(float lo, float hi){
  union { __hip_bfloat162 b; uint u; } x;
  x.b = __float22bfloat162_rn(make_float2(lo, hi));
  return x.u;
}
__device__ __forceinline__ float silu_f(float x){
  return x * __builtin_amdgcn_rcpf(1.0f + __expf(-x));
}

// ---------------- prep kernels ----------------

// merged: edge-count atomics + node init (speed0 folded into velw4.w)
__global__ __launch_bounds__(256) void k_count2(const int* __restrict__ erow,
    int* __restrict__ counts, const float* __restrict__ loc,
    const float* __restrict__ vel0, float4* __restrict__ coordw4,
    float4* __restrict__ velw4){
  int gid = blockIdx.x*256 + threadIdx.x;
  if (gid < EE) atomicAdd(&counts[erow[gid]], 1);
  if (gid < NN){
    float vx = vel0[gid*3+0], vy = vel0[gid*3+1], vz = vel0[gid*3+2];
    float sp = sqrtf(vx*vx + vy*vy + vz*vz);
    velw4[gid] = make_float4(vx, vy, vz, sp);
    coordw4[gid] = make_float4(loc[gid*3+0], loc[gid*3+1], loc[gid*3+2], 0.0f);
  }
}

__global__ __launch_bounds__(256) void k_bsum(const int* __restrict__ counts, int* __restrict__ bsum){
  __shared__ int sm[4];
  int tid = threadIdx.x;
  int i = blockIdx.x*256 + tid;
  int v = (i < NN) ? counts[i] : 0;
  #pragma unroll
  for (int off = 1; off < 64; off <<= 1) v += __shfl_xor(v, off);
  if ((tid & 63) == 0) sm[tid >> 6] = v;
  __syncthreads();
  if (tid == 0) bsum[blockIdx.x] = sm[0] + sm[1] + sm[2] + sm[3];
}

__global__ __launch_bounds__(256) void k_bscan(const int* __restrict__ bsum, int* __restrict__ bbase){
  __shared__ int sm[256];
  int tid = threadIdx.x;
  int v = (tid < 196) ? bsum[tid] : 0;
  sm[tid] = v;
  __syncthreads();
  #pragma unroll
  for (int off = 1; off < 256; off <<= 1){
    int t = (tid >= off) ? sm[tid - off] : 0;
    __syncthreads();
    sm[tid] += t;
    __syncthreads();
  }
  if (tid < 196) bbase[tid] = sm[tid] - v;   // exclusive
}

__global__ __launch_bounds__(256) void k_scatter(const int* __restrict__ counts,
    const int* __restrict__ bbase, int* __restrict__ cursor){
  __shared__ int sm[256];
  int tid = threadIdx.x;
  int i = blockIdx.x*256 + tid;
  int v = (i < NN) ? counts[i] : 0;
  sm[tid] = v;
  __syncthreads();
  #pragma unroll
  for (int off = 1; off < 256; off <<= 1){
    int t = (tid >= off) ? sm[tid - off] : 0;
    __syncthreads();
    sm[tid] += t;
    __syncthreads();
  }
  if (i < NN) cursor[i] = bbase[blockIdx.x] + sm[tid] - v;
}

// build CSR-sorted edge records {row, col, ea0, ea1}
__global__ __launch_bounds__(256) void k_fill(const int* __restrict__ erow,
    const int* __restrict__ ecol, const float* __restrict__ eattr,
    int* __restrict__ cursor, int4* __restrict__ erec){
  int e = blockIdx.x*256 + threadIdx.x;
  if (e < EE){
    int r = erow[e];
    int pos = atomicAdd(&cursor[r], 1);
    int4 rec;
    rec.x = r;
    rec.y = ecol[e];
    rec.z = __float_as_int(eattr[(size_t)e*2 + 0]);
    rec.w = __float_as_int(eattr[(size_t)e*2 + 1]);
    erec[pos] = rec;
  }
}

// pack weights:
//  edge weights in 32x32x16 frag order: unit (kt,mt) of 512 elems; elem (lane,i):
//    k = kt*16 + (lane>>5)*8 + i ; col = mt*32 + (lane&31)
//  eW1 K=144 (9 kt): k<131 -> eW1 ; k==131 -> b1 (bias row, pairs with const-1 feature) ; else 0
//  node weights in 16x16x32 frag order (unchanged).
// elem offsets: eW1p32 0..9215, eW2p32 9216..13311, cW1p32 13312..17407,
//               nW1p 17408..25599, nW2p 25600..29695, vW1p 29696..33791
__global__ __launch_bounds__(256) void k_packall(const float* __restrict__ eW1,
    const float* __restrict__ b1, const float* __restrict__ eW2,
    const float* __restrict__ cW1, const float* __restrict__ nW1,
    const float* __restrict__ nW2, const float* __restrict__ vW1,
    ushort* __restrict__ dst){
  int idx = blockIdx.x*256 + threadIdx.x;
  if (idx >= 33792) return;
  float v;
  if (idx < 17408){
    int rel, ktbase; const float* src; int isW1 = 0;
    if (idx < 9216){ rel = idx; src = eW1; isW1 = 1; }
    else if (idx < 13312){ rel = idx - 9216; src = eW2; }
    else { rel = idx - 13312; src = cW1; }
    int u = rel >> 9;           // (kt*2+mt)
    int kt = u >> 1, mt = u & 1;
    int within = rel & 511;
    int lane = within >> 3, i = within & 7;
    int k = kt*16 + (lane>>5)*8 + i;
    int col = mt*32 + (lane & 31);
    if (isW1){
      if (k < 131) v = src[k*64 + col];
      else if (k == 131) v = b1[col];
      else v = 0.0f;
    } else {
      v = (k < 64) ? src[k*64 + col] : 0.0f;
    }
  } else {
    int rel = idx - 17408;
    const float* src; int kt; int Ksrc;
    if (rel < 8192){ src = nW1; kt = rel >> 11; Ksrc = 128; }
    else if (rel < 12288){ src = nW2; kt = (rel - 8192) >> 11; Ksrc = 64; }
    else { src = vW1; kt = (rel - 12288) >> 11; Ksrc = 64; }
    int within = rel & 2047;
    int i = within & 7;
    int lane = (within >> 3) & 63;
    int ct = (within >> 9) & 3;
    int k = kt*32 + (lane>>4)*8 + i;
    int col = ct*16 + (lane & 15);
    v = (k < Ksrc) ? src[k*64 + col] : 0.0f;
  }
  dst[idx] = f2b(v);
}

__global__ __launch_bounds__(256) void k_embed(const float* __restrict__ his,
    const float* __restrict__ embW, const float* __restrict__ embB,
    float* __restrict__ h, ushort* __restrict__ hb){
  int idx = blockIdx.x*256 + threadIdx.x;
  if (idx >= NN*HD) return;
  int n = idx >> 6, j = idx & 63;
  float s = embB[j];
  #pragma unroll
  for (int k = 0; k < 8; ++k) s += his[n*8 + k] * embW[k*64 + j];
  h[idx] = s;
  hb[idx] = f2b(s);
}

// ---------------- edge MFMA kernel: 32x32x16, all-swapped ----------------
// Per wave: 32 edges (e = lane&31), h = lane>>5 selects k-half / feature-half.
// D = W^T · X^T : lane(e,h) reg r holds X[edge e][feat mt*32 + (r&3)+8*(r>>2)+4*h].
// LDS XMT: per-edge packed bf16 rows, stride 38 words (word w = feat pair 2w,2w+1).
__global__ __launch_bounds__(256) void k_edge(
    const ushort* __restrict__ hb, const float4* __restrict__ coord4,
    const int4* __restrict__ erec,
    const ushort* __restrict__ W1p, const ushort* __restrict__ W2p, const ushort* __restrict__ C1p,
    const float* __restrict__ b2, const float* __restrict__ cb1, const float* __restrict__ cw2,
    float* __restrict__ aggf)
{
  __shared__ __align__(16) uint XMT[128*38];
  __shared__ __align__(16) float TRL[128*4];
  const int tid = threadIdx.x;
  const int wave = tid >> 6, lane = tid & 63;
  const int e = lane & 31, h = lane >> 5;
  const int wt = wave * 32;
  const int slot = blockIdx.x*128 + wt + e;

  int4 er = erec[slot];
  const int rA = er.x, cA = er.y;

  // B-frags (edge data), K=144
  short8 bf[9];
  #pragma unroll
  for (int kt = 0; kt < 4; ++kt)
    bf[kt] = *reinterpret_cast<const short8*>(hb + (size_t)rA*HD + kt*16 + h*8);
  #pragma unroll
  for (int kt = 0; kt < 4; ++kt)
    bf[4+kt] = *reinterpret_cast<const short8*>(hb + (size_t)cA*HD + kt*16 + h*8);
  float4 crd = coord4[rA], ccd = coord4[cA];
  float dx = crd.x-ccd.x, dy = crd.y-ccd.y, dz = crd.z-ccd.z;
  float radial = dx*dx + dy*dy + dz*dz;
  short8 t8 = {0,0,0,0,0,0,0,0};
  if (h == 0){
    t8[0] = (short)f2b(radial);
    t8[1] = (short)f2b(__int_as_float(er.z));
    t8[2] = (short)f2b(__int_as_float(er.w));
    t8[3] = (short)0x3F80;   // 1.0 -> pairs with b1 packed at k=131
  }
  bf[8] = t8;

  const short8* W1f = reinterpret_cast<const short8*>(W1p);
  const short8* W2f = reinterpret_cast<const short8*>(W2p);
  const short8* C1f = reinterpret_cast<const short8*>(C1p);

  // GEMM1 (bias via k=131)
  f32x16 acc[2];
  #pragma unroll
  for (int mt = 0; mt < 2; ++mt)
    #pragma unroll
    for (int r = 0; r < 16; ++r) acc[mt][r] = 0.0f;
  #pragma unroll
  for (int kt = 0; kt < 9; ++kt){
    #pragma unroll
    for (int mt = 0; mt < 2; ++mt)
      acc[mt] = __builtin_amdgcn_mfma_f32_32x32x16_bf16(W1f[(kt*2+mt)*64 + lane], bf[kt], acc[mt], 0,0,0);
  }
  const int wrow = (wt + e)*38;
  #pragma unroll
  for (int mt = 0; mt < 2; ++mt){
    #pragma unroll
    for (int q = 0; q < 4; ++q){
      uint u0 = pk2(silu_f(acc[mt][4*q+0]), silu_f(acc[mt][4*q+1]));
      uint u1 = pk2(silu_f(acc[mt][4*q+2]), silu_f(acc[mt][4*q+3]));
      *reinterpret_cast<uint2v*>(&XMT[wrow + mt*16 + q*4 + h*2]) = (uint2v){u0, u1};
    }
  }
  __builtin_amdgcn_sched_barrier(0);
  short8 xf[4];
  #pragma unroll
  for (int kt = 0; kt < 4; ++kt)
    xf[kt] = *reinterpret_cast<const short8*>(&XMT[wrow + kt*8 + h*4]);

  // GEMM2: m = silu(X1 @ W2 + b2)
  f32x16 acc2[2];
  #pragma unroll
  for (int mt = 0; mt < 2; ++mt){
    #pragma unroll
    for (int q = 0; q < 4; ++q){
      f32x4 bq = *reinterpret_cast<const f32x4*>(b2 + mt*32 + q*8 + h*4);
      #pragma unroll
      for (int r = 0; r < 4; ++r) acc2[mt][4*q+r] = bq[r];
    }
  }
  #pragma unroll
  for (int kt = 0; kt < 4; ++kt){
    #pragma unroll
    for (int mt = 0; mt < 2; ++mt)
      acc2[mt] = __builtin_amdgcn_mfma_f32_32x32x16_bf16(W2f[(kt*2+mt)*64 + lane], xf[kt], acc2[mt], 0,0,0);
  }
  #pragma unroll
  for (int mt = 0; mt < 2; ++mt){
    #pragma unroll
    for (int q = 0; q < 4; ++q){
      uint u0 = pk2(silu_f(acc2[mt][4*q+0]), silu_f(acc2[mt][4*q+1]));
      uint u1 = pk2(silu_f(acc2[mt][4*q+2]), silu_f(acc2[mt][4*q+3]));
      *reinterpret_cast<uint2v*>(&XMT[wrow + mt*16 + q*4 + h*2]) = (uint2v){u0, u1};
    }
  }
  __builtin_amdgcn_sched_barrier(0);
  short8 xg[4];
  #pragma unroll
  for (int kt = 0; kt < 4; ++kt)
    xg[kt] = *reinterpret_cast<const short8*>(&XMT[wrow + kt*8 + h*4]);

  // GEMM3: X3 = silu(m @ cW1 + cb1) ; w = X3 @ cW2
  f32x16 acc3[2];
  #pragma unroll
  for (int mt = 0; mt < 2; ++mt){
    #pragma unroll
    for (int q = 0; q < 4; ++q){
      f32x4 bq = *reinterpret_cast<const f32x4*>(cb1 + mt*32 + q*8 + h*4);
      #pragma unroll
      for (int r = 0; r < 4; ++r) acc3[mt][4*q+r] = bq[r];
    }
  }
  #pragma unroll
  for (int kt = 0; kt < 4; ++kt){
    #pragma unroll
    for (int mt = 0; mt < 2; ++mt)
      acc3[mt] = __builtin_amdgcn_mfma_f32_32x32x16_bf16(C1f[(kt*2+mt)*64 + lane], xg[kt], acc3[mt], 0,0,0);
  }
  float pw = 0.0f;
  #pragma unroll
  for (int mt = 0; mt < 2; ++mt){
    #pragma unroll
    for (int q = 0; q < 4; ++q){
      f32x4 cwq = *reinterpret_cast<const f32x4*>(cw2 + mt*32 + q*8 + h*4);
      #pragma unroll
      for (int r = 0; r < 4; ++r) pw += silu_f(acc3[mt][4*q+r]) * cwq[r];
    }
  }
  pw += __shfl_xor(pw, 32);
  if (h == 0){
    f32x4 t = {dx*pw, dy*pw, dz*pw, 0.0f};
    *reinterpret_cast<f32x4*>(&TRL[(wt + e)*4]) = t;
  }
  __builtin_amdgcn_sched_barrier(0);

  // per-wave segmented sum over 32 CSR-sorted edges -> atomic flush
  const ushort* mvals = reinterpret_cast<const ushort*>(XMT);
  float sum = 0.f, ts = 0.f;
  int rcur = __builtin_amdgcn_readlane(rA, 0);
  #pragma unroll
  for (int i = 0; i < 32; ++i){
    sum += b2f(mvals[(wt + i)*76 + lane]);
    if (lane < 3) ts += TRL[(wt + i)*4 + lane];
    int rnext = (i < 31) ? __builtin_amdgcn_readlane(rA, i+1) : -1;
    if (rnext != rcur){
      atomicAdd(&aggf[(size_t)rcur*AGS + lane], sum);
      if (lane < 3) atomicAdd(&aggf[(size_t)rcur*AGS + 64 + lane], ts);
      sum = 0.f; ts = 0.f; rcur = rnext;
    }
  }
}

// ---------------- node MFMA kernel (+fused vel/coord update, +aggf re-zero) ----------------
__global__ __launch_bounds__(256) void k_node(
    const ushort* __restrict__ hb, float* __restrict__ aggf, const float* __restrict__ h_in,
    const ushort* __restrict__ nW1p, const ushort* __restrict__ nW2p, const ushort* __restrict__ vW1p,
    const float* __restrict__ nb1, const float* __restrict__ nb2,
    const float* __restrict__ vb1, const float* __restrict__ vW2, const float* __restrict__ vb2,
    const int* __restrict__ counts, float4* __restrict__ velw4, float4* __restrict__ coordw4,
    float* __restrict__ h_out, ushort* __restrict__ hb_out,
    float* __restrict__ xout, float* __restrict__ vout, int last)
{
  __shared__ __align__(16) ushort HID[64*88];
  __shared__ float VS[64];
  const int tid = threadIdx.x;
  const int wave = tid >> 6, lane = tid & 63;
  const int c = lane & 15, g = lane >> 4;
  const int wt = wave * 16;
  const int nbase = blockIdx.x * 64;
  int nA = nbase + wt + c;
  int nAc = (nA < NN) ? nA : (NN-1);

  short8 af[4];
  af[0] = *reinterpret_cast<const short8*>(hb + (size_t)nAc*HD + g*8);
  af[1] = *reinterpret_cast<const short8*>(hb + (size_t)nAc*HD + 32 + g*8);
  {
    const float* ag = aggf + (size_t)nAc*AGS;
    f32x4 q0 = *reinterpret_cast<const f32x4*>(ag + g*8);
    f32x4 q1 = *reinterpret_cast<const f32x4*>(ag + g*8 + 4);
    f32x4 q2 = *reinterpret_cast<const f32x4*>(ag + 32 + g*8);
    f32x4 q3 = *reinterpret_cast<const f32x4*>(ag + 32 + g*8 + 4);
    union FB { ushort u[8]; short8 s; };
    FB f2_, f3_;
    #pragma unroll
    for (int i = 0; i < 4; ++i){ f2_.u[i] = f2b(q0[i]); f2_.u[4+i] = f2b(q1[i]); }
    #pragma unroll
    for (int i = 0; i < 4; ++i){ f3_.u[i] = f2b(q2[i]); f3_.u[4+i] = f2b(q3[i]); }
    af[2] = f2_.s;
    af[3] = f3_.s;
  }
  const short8* N1f = reinterpret_cast<const short8*>(nW1p);
  const short8* N2f = reinterpret_cast<const short8*>(nW2p);
  const short8* V1f = reinterpret_cast<const short8*>(vW1p);

  f32x4 acc[4];
  #pragma unroll
  for (int ct = 0; ct < 4; ++ct){
    float bb = nb1[ct*16 + c];
    acc[ct] = (f32x4){bb,bb,bb,bb};
  }
  #pragma unroll
  for (int kt = 0; kt < 4; ++kt){
    #pragma unroll
    for (int ct = 0; ct < 4; ++ct){
      acc[ct] = __builtin_amdgcn_mfma_f32_16x16x32_bf16(af[kt], N1f[(kt*4+ct)*64 + lane], acc[ct], 0,0,0);
    }
  }
  #pragma unroll
  for (int ct = 0; ct < 4; ++ct){
    int col = ct*16 + c;
    #pragma unroll
    for (int r = 0; r < 4; ++r){
      HID[(wt + g*4 + r)*88 + col] = f2b(silu_f(acc[ct][r]));
    }
  }

  // v MLP (uses h only)
  f32x4 av[4];
  #pragma unroll
  for (int ct = 0; ct < 4; ++ct){
    float bb = vb1[ct*16 + c];
    av[ct] = (f32x4){bb,bb,bb,bb};
  }
  #pragma unroll
  for (int kt = 0; kt < 2; ++kt){
    #pragma unroll
    for (int ct = 0; ct < 4; ++ct){
      av[ct] = __builtin_amdgcn_mfma_f32_16x16x32_bf16(af[kt], V1f[(kt*4+ct)*64 + lane], av[ct], 0,0,0);
    }
  }
  float pw[4] = {0.f,0.f,0.f,0.f};
  #pragma unroll
  for (int ct = 0; ct < 4; ++ct){
    float vw = vW2[ct*16 + c];
    #pragma unroll
    for (int r = 0; r < 4; ++r) pw[r] += silu_f(av[ct][r]) * vw;
  }
  #pragma unroll
  for (int off = 1; off < 16; off <<= 1){
    #pragma unroll
    for (int r = 0; r < 4; ++r) pw[r] += __shfl_xor(pw[r], off, 16);
  }
  if (c == 0){
    float vbias = vb2[0];
    #pragma unroll
    for (int r = 0; r < 4; ++r) VS[wt + g*4 + r] = pw[r] + vbias;
  }

  // node MLP second layer (reads HID written by this wave only)
  short8 h0 = *reinterpret_cast<const short8*>(&HID[(wt + c)*88 + g*8]);
  short8 h1 = *reinterpret_cast<const short8*>(&HID[(wt + c)*88 + 32 + g*8]);
  f32x4 a2[4];
  #pragma unroll
  for (int ct = 0; ct < 4; ++ct){
    float bb = nb2[ct*16 + c];
    a2[ct] = (f32x4){bb,bb,bb,bb};
  }
  #pragma unroll
  for (int ct = 0; ct < 4; ++ct)
    a2[ct] = __builtin_amdgcn_mfma_f32_16x16x32_bf16(h0, N2f[(0*4+ct)*64 + lane], a2[ct], 0,0,0);
  #pragma unroll
  for (int ct = 0; ct < 4; ++ct)
    a2[ct] = __builtin_amdgcn_mfma_f32_16x16x32_bf16(h1, N2f[(1*4+ct)*64 + lane], a2[ct], 0,0,0);
  #pragma unroll
  for (int ct = 0; ct < 4; ++ct){
    int col = ct*16 + c;
    #pragma unroll
    for (int r = 0; r < 4; ++r){
      int n = nbase + wt + g*4 + r;
      if (n < NN){
        size_t off = (size_t)n*HD + col;
        float v = 2.0f*h_in[off] + a2[ct][r];
        h_out[off] = v;
        hb_out[off] = f2b(v);
      }
    }
  }

  // fused vel/coord update
  __syncthreads();
  if (tid < 64){
    int n = nbase + tid;
    if (n < NN){
      float vsn = VS[tid];
      float inv = 1.0f / fmaxf((float)counts[n], 1.0f);
      const float* ag = aggf + (size_t)n*AGS + 64;
      float ax = ag[0]*inv, ay = ag[1]*inv, az = ag[2]*inv;
      float4 vv = velw4[n];
      float4 cc = coordw4[n];
      float v0 = vsn*vv.x + ax*(1.0f/7.0f);
      float v1 = vsn*vv.y + ay*(1.0f/7.0f);
      float v2 = vsn*vv.z + az*(1.0f/7.0f);
      float s = vv.w / (sqrtf(v0*v0 + v1*v1 + v2*v2) + 1e-8f);
      v0 *= s; v1 *= s; v2 *= s;
      float c0 = cc.x + v0*(1.0f/7.0f);
      float c1 = cc.y + v1*(1.0f/7.0f);
      float c2 = cc.z + v2*(1.0f/7.0f);
      if (last){
        vout[n*3+0] = v0; vout[n*3+1] = v1; vout[n*3+2] = v2;
        xout[n*3+0] = c0; xout[n*3+1] = c1; xout[n*3+2] = c2;
      } else {
        velw4[n] = make_float4(v0, v1, v2, vv.w);
        coordw4[n] = make_float4(c0, c1, c2, 0.0f);
      }
    }
  }

  // re-zero this block's aggf rows for the next layer (replaces per-layer memset)
  __syncthreads();
  int nvalid = NN - nbase; if (nvalid > 64) nvalid = 64;
  float* zb = aggf + (size_t)nbase*AGS;
  for (int idx2 = tid; idx2 < nvalid*AGS; idx2 += 256) zb[idx2] = 0.0f;
}

// ---------------- launcher ----------------
extern "C" void kernel_launch(void* const* d_in, const int* in_sizes, int n_in,
                              void* d_out, int out_size, void* d_ws, size_t ws_size,
                              hipStream_t stream)
{
  const float* his  = (const float*)d_in[0];
  const float* loc  = (const float*)d_in[1];
  const int*   edges= (const int*)d_in[2];
  const float* vel0 = (const float*)d_in[3];
  const float* eatt = (const float*)d_in[4];
  const float* embW = (const float*)d_in[5];
  const float* embB = (const float*)d_in[6];
  const float* eW1  = (const float*)d_in[7];
  const float* eB1  = (const float*)d_in[8];
  const float* eW2  = (const float*)d_in[9];
  const float* eB2  = (const float*)d_in[10];
  const float* cW1  = (const float*)d_in[11];
  const float* cB1  = (const float*)d_in[12];
  const float* cW2  = (const float*)d_in[13];
  const float* vW1  = (const float*)d_in[14];
  const float* vB1  = (const float*)d_in[15];
  const float* vW2  = (const float*)d_in[16];
  const float* vB2  = (const float*)d_in[17];
  const float* nW1  = (const float*)d_in[18];
  const float* nB1  = (const float*)d_in[19];
  const float* nW2  = (const float*)d_in[20];
  const float* nB2  = (const float*)d_in[21];
  const int* erow = edges;
  const int* ecol = edges + EE;

  char* ws = (char*)d_ws;
  size_t off = 0;
  auto alloc = [&](size_t bytes)->char*{
    char* p = ws + off;
    off = (off + bytes + 255) & ~(size_t)255;
    return p;
  };
  ushort* hb     = (ushort*)alloc((size_t)NN*HD*2);
  int*    counts = (int*)   alloc((size_t)NN*4);
  int*    cursor = (int*)   alloc((size_t)NN*4);
  int*    bsum   = (int*)   alloc(256*4);
  int*    bbase  = (int*)   alloc(256*4);
  float4* coordw4= (float4*)alloc((size_t)NN*16);
  float4* velw4  = (float4*)alloc((size_t)NN*16);
  float*  aggf   = (float*) alloc((size_t)NN*AGS*4);
  ushort* allp   = (ushort*)alloc(33792*2);
  int4*   erec   = (int4*)  alloc((size_t)EE*16);

  ushort* eW1p32 = allp;            // 9216
  ushort* eW2p32 = allp + 9216;     // 4096
  ushort* cW1p32 = allp + 13312;    // 4096
  ushort* nW1p   = allp + 17408;    // 8192
  ushort* nW2p   = allp + 25600;    // 4096
  ushort* vW1p   = allp + 29696;    // 4096

  float* xout = (float*)d_out;                    // [N,3]
  float* hout = (float*)d_out + (size_t)NN*3;     // [N,64] — doubles as fp32 h buffer
  float* vout = (float*)d_out + (size_t)NN*3 + (size_t)NN*HD; // [N,3]

  hipMemsetAsync(counts, 0, (size_t)NN*4, stream);
  hipMemsetAsync(aggf, 0, (size_t)NN*AGS*4, stream);
  k_count2<<<3125,256,0,stream>>>(erow, counts, loc, vel0, coordw4, velw4);
  k_bsum<<<196,256,0,stream>>>(counts, bsum);
  k_bscan<<<1,256,0,stream>>>(bsum, bbase);
  k_scatter<<<196,256,0,stream>>>(counts, bbase, cursor);
  k_fill<<<3125,256,0,stream>>>(erow, ecol, eatt, cursor, erec);
  k_packall<<<132,256,0,stream>>>(eW1, eB1, eW2, cW1, nW1, nW2, vW1, allp);
  k_embed<<<12500,256,0,stream>>>(his, embW, embB, hout, hb);

  for (int L = 0; L < 4; ++L){
    k_edge<<<6250,256,0,stream>>>(hb, coordw4, erec,
        eW1p32, eW2p32, cW1p32, eB2, cB1, cW2, aggf);
    k_node<<<782,256,0,stream>>>(hb, aggf, hout, nW1p, nW2p, vW1p,
        nB1, nB2, vB1, vW2, vB2, counts, velw4, coordw4,
        hout, hb, xout, vout, (L==3) ? 1 : 0);
  }
}

// Round 7
// 513.457 us; speedup vs baseline: 2.0911x; 1.0360x over previous
//
#include <hip/hip_runtime.h>
#include <hip/hip_bf16.h>
#include <stdint.h>

#define NN 50000
#define EE 800000
#define HD 64
#define AGS 72   // aggf row stride: 64 feats + 3 trans + pad

typedef short short8 __attribute__((ext_vector_type(8)));
typedef float f32x4  __attribute__((ext_vector_type(4)));
typedef float f32x16 __attribute__((ext_vector_type(16)));
typedef uint  uint2v __attribute__((ext_vector_type(2)));

__device__ __forceinline__ float b2f(ushort u){ return __uint_as_float(((uint32_t)u)<<16); }
__device__ __forceinline__ ushort f2b(float f){
  uint32_t u = __float_as_uint(f);
  u += 0x7fffu + ((u>>16)&1u);
  return (ushort)(u>>16);
}
__device__ __forceinline__ uint pk2(float lo, float hi){
  union { __hip_bfloat162 b; uint u; } x;
  x.b = __float22bfloat162_rn(make_float2(lo, hi));
  return x.u;
}
__device__ __forceinline__ float silu_f(float x){
  return x * __builtin_amdgcn_rcpf(1.0f + __expf(-x));
}

// ---------------- prep kernels ----------------

// merged: edge-count atomics + node init (speed0 folded into velw4.w)
__global__ __launch_bounds__(256) void k_count2(const int* __restrict__ erow,
    int* __restrict__ counts, const float* __restrict__ loc,
    const float* __restrict__ vel0, float4* __restrict__ coordw4,
    float4* __restrict__ velw4){
  int gid = blockIdx.x*256 + threadIdx.x;
  if (gid < EE) atomicAdd(&counts[erow[gid]], 1);
  if (gid < NN){
    float vx = vel0[gid*3+0], vy = vel0[gid*3+1], vz = vel0[gid*3+2];
    float sp = sqrtf(vx*vx + vy*vy + vz*vz);
    velw4[gid] = make_float4(vx, vy, vz, sp);
    coordw4[gid] = make_float4(loc[gid*3+0], loc[gid*3+1], loc[gid*3+2], 0.0f);
  }
}

__global__ __launch_bounds__(256) void k_bsum(const int* __restrict__ counts, int* __restrict__ bsum){
  __shared__ int sm[4];
  int tid = threadIdx.x;
  int i = blockIdx.x*256 + tid;
  int v = (i < NN) ? counts[i] : 0;
  #pragma unroll
  for (int off = 1; off < 64; off <<= 1) v += __shfl_xor(v, off);
  if ((tid & 63) == 0) sm[tid >> 6] = v;
  __syncthreads();
  if (tid == 0) bsum[blockIdx.x] = sm[0] + sm[1] + sm[2] + sm[3];
}

__global__ __launch_bounds__(256) void k_bscan(const int* __restrict__ bsum, int* __restrict__ bbase){
  __shared__ int sm[256];
  int tid = threadIdx.x;
  int v = (tid < 196) ? bsum[tid] : 0;
  sm[tid] = v;
  __syncthreads();
  #pragma unroll
  for (int off = 1; off < 256; off <<= 1){
    int t = (tid >= off) ? sm[tid - off] : 0;
    __syncthreads();
    sm[tid] += t;
    __syncthreads();
  }
  if (tid < 196) bbase[tid] = sm[tid] - v;   // exclusive
}

__global__ __launch_bounds__(256) void k_scatter(const int* __restrict__ counts,
    const int* __restrict__ bbase, int* __restrict__ cursor){
  __shared__ int sm[256];
  int tid = threadIdx.x;
  int i = blockIdx.x*256 + tid;
  int v = (i < NN) ? counts[i] : 0;
  sm[tid] = v;
  __syncthreads();
  #pragma unroll
  for (int off = 1; off < 256; off <<= 1){
    int t = (tid >= off) ? sm[tid - off] : 0;
    __syncthreads();
    sm[tid] += t;
    __syncthreads();
  }
  if (i < NN) cursor[i] = bbase[blockIdx.x] + sm[tid] - v;
}

// build CSR-sorted edge records {row, col, ea0, ea1}
__global__ __launch_bounds__(256) void k_fill(const int* __restrict__ erow,
    const int* __restrict__ ecol, const float* __restrict__ eattr,
    int* __restrict__ cursor, int4* __restrict__ erec){
  int e = blockIdx.x*256 + threadIdx.x;
  if (e < EE){
    int r = erow[e];
    int pos = atomicAdd(&cursor[r], 1);
    int4 rec;
    rec.x = r;
    rec.y = ecol[e];
    rec.z = __float_as_int(eattr[(size_t)e*2 + 0]);
    rec.w = __float_as_int(eattr[(size_t)e*2 + 1]);
    erec[pos] = rec;
  }
}

// pack weights (see round-6 comment block; layouts unchanged)
__global__ __launch_bounds__(256) void k_packall(const float* __restrict__ eW1,
    const float* __restrict__ b1, const float* __restrict__ eW2,
    const float* __restrict__ cW1, const float* __restrict__ nW1,
    const float* __restrict__ nW2, const float* __restrict__ vW1,
    ushort* __restrict__ dst){
  int idx = blockIdx.x*256 + threadIdx.x;
  if (idx >= 33792) return;
  float v;
  if (idx < 17408){
    int rel; const float* src; int isW1 = 0;
    if (idx < 9216){ rel = idx; src = eW1; isW1 = 1; }
    else if (idx < 13312){ rel = idx - 9216; src = eW2; }
    else { rel = idx - 13312; src = cW1; }
    int u = rel >> 9;           // (kt*2+mt)
    int kt = u >> 1, mt = u & 1;
    int within = rel & 511;
    int lane = within >> 3, i = within & 7;
    int k = kt*16 + (lane>>5)*8 + i;
    int col = mt*32 + (lane & 31);
    if (isW1){
      if (k < 131) v = src[k*64 + col];
      else if (k == 131) v = b1[col];
      else v = 0.0f;
    } else {
      v = (k < 64) ? src[k*64 + col] : 0.0f;
    }
  } else {
    int rel = idx - 17408;
    const float* src; int kt; int Ksrc;
    if (rel < 8192){ src = nW1; kt = rel >> 11; Ksrc = 128; }
    else if (rel < 12288){ src = nW2; kt = (rel - 8192) >> 11; Ksrc = 64; }
    else { src = vW1; kt = (rel - 12288) >> 11; Ksrc = 64; }
    int within = rel & 2047;
    int i = within & 7;
    int lane = (within >> 3) & 63;
    int ct = (within >> 9) & 3;
    int k = kt*32 + (lane>>4)*8 + i;
    int col = ct*16 + (lane & 15);
    v = (k < Ksrc) ? src[k*64 + col] : 0.0f;
  }
  dst[idx] = f2b(v);
}

__global__ __launch_bounds__(256) void k_embed(const float* __restrict__ his,
    const float* __restrict__ embW, const float* __restrict__ embB,
    float* __restrict__ h, ushort* __restrict__ hb){
  int idx = blockIdx.x*256 + threadIdx.x;
  if (idx >= NN*HD) return;
  int n = idx >> 6, j = idx & 63;
  float s = embB[j];
  #pragma unroll
  for (int k = 0; k < 8; ++k) s += his[n*8 + k] * embW[k*64 + j];
  h[idx] = s;
  hb[idx] = f2b(s);
}

// ---------------- edge MFMA kernel: 32x32x16, all-swapped, sequential-mt ----------------
// Per wave: 32 edges (e = lane&31), h = lane>>5.
// D = W^T · X^T : lane(e,h) reg r holds X[edge e][feat mt*32 + (r&3)+8*(r>>2)+4*h].
// Feature halves (mt) processed SEQUENTIALLY to keep one f32x16 accumulator live
// (register pressure -> occupancy; round-6 was 3 waves/SIMD).
__global__ __launch_bounds__(256, 4) void k_edge(
    const ushort* __restrict__ hb, const float4* __restrict__ coord4,
    const int4* __restrict__ erec,
    const ushort* __restrict__ W1p, const ushort* __restrict__ W2p, const ushort* __restrict__ C1p,
    const float* __restrict__ b2, const float* __restrict__ cb1, const float* __restrict__ cw2,
    float* __restrict__ aggf)
{
  __shared__ __align__(16) uint XMT[128*38];
  __shared__ __align__(16) float TRL[128*4];
  const int tid = threadIdx.x;
  const int wave = tid >> 6, lane = tid & 63;
  const int e = lane & 31, h = lane >> 5;
  const int wt = wave * 32;
  const int slot = blockIdx.x*128 + wt + e;

  int4 er = erec[slot];
  const int rA = er.x, cA = er.y;

  float4 crd = coord4[rA], ccd = coord4[cA];
  float dx = crd.x-ccd.x, dy = crd.y-ccd.y, dz = crd.z-ccd.z;
  float radial = dx*dx + dy*dy + dz*dz;

  const short8* W1f = reinterpret_cast<const short8*>(W1p);
  const short8* W2f = reinterpret_cast<const short8*>(W2p);
  const short8* C1f = reinterpret_cast<const short8*>(C1p);
  const int wrow = (wt + e)*38;

  // GEMM1: bias folded at k=131; sequential over mt
  {
    short8 bf[9];
    #pragma unroll
    for (int kt = 0; kt < 4; ++kt)
      bf[kt] = *reinterpret_cast<const short8*>(hb + (size_t)rA*HD + kt*16 + h*8);
    #pragma unroll
    for (int kt = 0; kt < 4; ++kt)
      bf[4+kt] = *reinterpret_cast<const short8*>(hb + (size_t)cA*HD + kt*16 + h*8);
    short8 t8 = {0,0,0,0,0,0,0,0};
    if (h == 0){
      t8[0] = (short)f2b(radial);
      t8[1] = (short)f2b(__int_as_float(er.z));
      t8[2] = (short)f2b(__int_as_float(er.w));
      t8[3] = (short)0x3F80;   // 1.0 -> pairs with b1 packed at k=131
    }
    bf[8] = t8;

    #pragma unroll 1
    for (int mt = 0; mt < 2; ++mt){
      f32x16 a;
      #pragma unroll
      for (int r = 0; r < 16; ++r) a[r] = 0.0f;
      #pragma unroll
      for (int kt = 0; kt < 9; ++kt)
        a = __builtin_amdgcn_mfma_f32_32x32x16_bf16(W1f[(kt*2+mt)*64 + lane], bf[kt], a, 0,0,0);
      #pragma unroll
      for (int q = 0; q < 4; ++q){
        uint u0 = pk2(silu_f(a[4*q+0]), silu_f(a[4*q+1]));
        uint u1 = pk2(silu_f(a[4*q+2]), silu_f(a[4*q+3]));
        *reinterpret_cast<uint2v*>(&XMT[wrow + mt*16 + q*4 + h*2]) = (uint2v){u0, u1};
      }
    }
  }
  __builtin_amdgcn_sched_barrier(0);

  // GEMM2: m = silu(X1 @ W2 + b2), sequential over mt
  {
    short8 xf[4];
    #pragma unroll
    for (int kt = 0; kt < 4; ++kt)
      xf[kt] = *reinterpret_cast<const short8*>(&XMT[wrow + kt*8 + h*4]);
    #pragma unroll 1
    for (int mt = 0; mt < 2; ++mt){
      f32x16 a;
      #pragma unroll
      for (int q = 0; q < 4; ++q){
        f32x4 bq = *reinterpret_cast<const f32x4*>(b2 + mt*32 + q*8 + h*4);
        #pragma unroll
        for (int r = 0; r < 4; ++r) a[4*q+r] = bq[r];
      }
      #pragma unroll
      for (int kt = 0; kt < 4; ++kt)
        a = __builtin_amdgcn_mfma_f32_32x32x16_bf16(W2f[(kt*2+mt)*64 + lane], xf[kt], a, 0,0,0);
      #pragma unroll
      for (int q = 0; q < 4; ++q){
        uint u0 = pk2(silu_f(a[4*q+0]), silu_f(a[4*q+1]));
        uint u1 = pk2(silu_f(a[4*q+2]), silu_f(a[4*q+3]));
        *reinterpret_cast<uint2v*>(&XMT[wrow + mt*16 + q*4 + h*2]) = (uint2v){u0, u1};
      }
    }
  }
  __builtin_amdgcn_sched_barrier(0);

  // GEMM3: X3 = silu(m @ cW1 + cb1); w = X3 @ cW2 ; sequential over mt
  float pw = 0.0f;
  {
    short8 xg[4];
    #pragma unroll
    for (int kt = 0; kt < 4; ++kt)
      xg[kt] = *reinterpret_cast<const short8*>(&XMT[wrow + kt*8 + h*4]);
    #pragma unroll 1
    for (int mt = 0; mt < 2; ++mt){
      f32x16 a;
      #pragma unroll
      for (int q = 0; q < 4; ++q){
        f32x4 bq = *reinterpret_cast<const f32x4*>(cb1 + mt*32 + q*8 + h*4);
        #pragma unroll
        for (int r = 0; r < 4; ++r) a[4*q+r] = bq[r];
      }
      #pragma unroll
      for (int kt = 0; kt < 4; ++kt)
        a = __builtin_amdgcn_mfma_f32_32x32x16_bf16(C1f[(kt*2+mt)*64 + lane], xg[kt], a, 0,0,0);
      #pragma unroll
      for (int q = 0; q < 4; ++q){
        f32x4 cwq = *reinterpret_cast<const f32x4*>(cw2 + mt*32 + q*8 + h*4);
        #pragma unroll
        for (int r = 0; r < 4; ++r) pw += silu_f(a[4*q+r]) * cwq[r];
      }
    }
  }
  pw += __shfl_xor(pw, 32);
  if (h == 0){
    f32x4 t = {dx*pw, dy*pw, dz*pw, 0.0f};
    *reinterpret_cast<f32x4*>(&TRL[(wt + e)*4]) = t;
  }
  __builtin_amdgcn_sched_barrier(0);

  // per-wave segmented sum over 32 CSR-sorted edges -> atomic flush
  const ushort* mvals = reinterpret_cast<const ushort*>(XMT);
  float sum = 0.f, ts = 0.f;
  int rcur = __builtin_amdgcn_readlane(rA, 0);
  #pragma unroll
  for (int i = 0; i < 32; ++i){
    sum += b2f(mvals[(wt + i)*76 + lane]);
    if (lane < 3) ts += TRL[(wt + i)*4 + lane];
    int rnext = (i < 31) ? __builtin_amdgcn_readlane(rA, i+1) : -1;
    if (rnext != rcur){
      atomicAdd(&aggf[(size_t)rcur*AGS + lane], sum);
      if (lane < 3) atomicAdd(&aggf[(size_t)rcur*AGS + 64 + lane], ts);
      sum = 0.f; ts = 0.f; rcur = rnext;
    }
  }
}

// ---------------- node MFMA kernel (+fused vel/coord update, +aggf re-zero) ----------------
__global__ __launch_bounds__(256) void k_node(
    const ushort* __restrict__ hb, float* __restrict__ aggf, const float* __restrict__ h_in,
    const ushort* __restrict__ nW1p, const ushort* __restrict__ nW2p, const ushort* __restrict__ vW1p,
    const float* __restrict__ nb1, const float* __restrict__ nb2,
    const float* __restrict__ vb1, const float* __restrict__ vW2, const float* __restrict__ vb2,
    const int* __restrict__ counts, float4* __restrict__ velw4, float4* __restrict__ coordw4,
    float* __restrict__ h_out, ushort* __restrict__ hb_out,
    float* __restrict__ xout, float* __restrict__ vout, int last)
{
  __shared__ __align__(16) ushort HID[64*88];
  __shared__ float VS[64];
  const int tid = threadIdx.x;
  const int wave = tid >> 6, lane = tid & 63;
  const int c = lane & 15, g = lane >> 4;
  const int wt = wave * 16;
  const int nbase = blockIdx.x * 64;
  int nA = nbase + wt + c;
  int nAc = (nA < NN) ? nA : (NN-1);

  short8 af[4];
  af[0] = *reinterpret_cast<const short8*>(hb + (size_t)nAc*HD + g*8);
  af[1] = *reinterpret_cast<const short8*>(hb + (size_t)nAc*HD + 32 + g*8);
  {
    const float* ag = aggf + (size_t)nAc*AGS;
    f32x4 q0 = *reinterpret_cast<const f32x4*>(ag + g*8);
    f32x4 q1 = *reinterpret_cast<const f32x4*>(ag + g*8 + 4);
    f32x4 q2 = *reinterpret_cast<const f32x4*>(ag + 32 + g*8);
    f32x4 q3 = *reinterpret_cast<const f32x4*>(ag + 32 + g*8 + 4);
    union FB { ushort u[8]; short8 s; };
    FB f2_, f3_;
    #pragma unroll
    for (int i = 0; i < 4; ++i){ f2_.u[i] = f2b(q0[i]); f2_.u[4+i] = f2b(q1[i]); }
    #pragma unroll
    for (int i = 0; i < 4; ++i){ f3_.u[i] = f2b(q2[i]); f3_.u[4+i] = f2b(q3[i]); }
    af[2] = f2_.s;
    af[3] = f3_.s;
  }
  const short8* N1f = reinterpret_cast<const short8*>(nW1p);
  const short8* N2f = reinterpret_cast<const short8*>(nW2p);
  const short8* V1f = reinterpret_cast<const short8*>(vW1p);

  f32x4 acc[4];
  #pragma unroll
  for (int ct = 0; ct < 4; ++ct){
    float bb = nb1[ct*16 + c];
    acc[ct] = (f32x4){bb,bb,bb,bb};
  }
  #pragma unroll
  for (int kt = 0; kt < 4; ++kt){
    #pragma unroll
    for (int ct = 0; ct < 4; ++ct){
      acc[ct] = __builtin_amdgcn_mfma_f32_16x16x32_bf16(af[kt], N1f[(kt*4+ct)*64 + lane], acc[ct], 0,0,0);
    }
  }
  #pragma unroll
  for (int ct = 0; ct < 4; ++ct){
    int col = ct*16 + c;
    #pragma unroll
    for (int r = 0; r < 4; ++r){
      HID[(wt + g*4 + r)*88 + col] = f2b(silu_f(acc[ct][r]));
    }
  }

  // v MLP (uses h only)
  f32x4 av[4];
  #pragma unroll
  for (int ct = 0; ct < 4; ++ct){
    float bb = vb1[ct*16 + c];
    av[ct] = (f32x4){bb,bb,bb,bb};
  }
  #pragma unroll
  for (int kt = 0; kt < 2; ++kt){
    #pragma unroll
    for (int ct = 0; ct < 4; ++ct){
      av[ct] = __builtin_amdgcn_mfma_f32_16x16x32_bf16(af[kt], V1f[(kt*4+ct)*64 + lane], av[ct], 0,0,0);
    }
  }
  float pw[4] = {0.f,0.f,0.f,0.f};
  #pragma unroll
  for (int ct = 0; ct < 4; ++ct){
    float vw = vW2[ct*16 + c];
    #pragma unroll
    for (int r = 0; r < 4; ++r) pw[r] += silu_f(av[ct][r]) * vw;
  }
  #pragma unroll
  for (int off = 1; off < 16; off <<= 1){
    #pragma unroll
    for (int r = 0; r < 4; ++r) pw[r] += __shfl_xor(pw[r], off, 16);
  }
  if (c == 0){
    float vbias = vb2[0];
    #pragma unroll
    for (int r = 0; r < 4; ++r) VS[wt + g*4 + r] = pw[r] + vbias;
  }

  // node MLP second layer (reads HID written by this wave only)
  short8 h0 = *reinterpret_cast<const short8*>(&HID[(wt + c)*88 + g*8]);
  short8 h1 = *reinterpret_cast<const short8*>(&HID[(wt + c)*88 + 32 + g*8]);
  f32x4 a2[4];
  #pragma unroll
  for (int ct = 0; ct < 4; ++ct){
    float bb = nb2[ct*16 + c];
    a2[ct] = (f32x4){bb,bb,bb,bb};
  }
  #pragma unroll
  for (int ct = 0; ct < 4; ++ct)
    a2[ct] = __builtin_amdgcn_mfma_f32_16x16x32_bf16(h0, N2f[(0*4+ct)*64 + lane], a2[ct], 0,0,0);
  #pragma unroll
  for (int ct = 0; ct < 4; ++ct)
    a2[ct] = __builtin_amdgcn_mfma_f32_16x16x32_bf16(h1, N2f[(1*4+ct)*64 + lane], a2[ct], 0,0,0);
  #pragma unroll
  for (int ct = 0; ct < 4; ++ct){
    int col = ct*16 + c;
    #pragma unroll
    for (int r = 0; r < 4; ++r){
      int n = nbase + wt + g*4 + r;
      if (n < NN){
        size_t off = (size_t)n*HD + col;
        float v = 2.0f*h_in[off] + a2[ct][r];
        h_out[off] = v;
        hb_out[off] = f2b(v);
      }
    }
  }

  // fused vel/coord update
  __syncthreads();
  if (tid < 64){
    int n = nbase + tid;
    if (n < NN){
      float vsn = VS[tid];
      float inv = 1.0f / fmaxf((float)counts[n], 1.0f);
      const float* ag = aggf + (size_t)n*AGS + 64;
      float ax = ag[0]*inv, ay = ag[1]*inv, az = ag[2]*inv;
      float4 vv = velw4[n];
      float4 cc = coordw4[n];
      float v0 = vsn*vv.x + ax*(1.0f/7.0f);
      float v1 = vsn*vv.y + ay*(1.0f/7.0f);
      float v2 = vsn*vv.z + az*(1.0f/7.0f);
      float s = vv.w / (sqrtf(v0*v0 + v1*v1 + v2*v2) + 1e-8f);
      v0 *= s; v1 *= s; v2 *= s;
      float c0 = cc.x + v0*(1.0f/7.0f);
      float c1 = cc.y + v1*(1.0f/7.0f);
      float c2 = cc.z + v2*(1.0f/7.0f);
      if (last){
        vout[n*3+0] = v0; vout[n*3+1] = v1; vout[n*3+2] = v2;
        xout[n*3+0] = c0; xout[n*3+1] = c1; xout[n*3+2] = c2;
      } else {
        velw4[n] = make_float4(v0, v1, v2, vv.w);
        coordw4[n] = make_float4(c0, c1, c2, 0.0f);
      }
    }
  }

  // re-zero this block's aggf rows for the next layer (replaces per-layer memset)
  __syncthreads();
  int nvalid = NN - nbase; if (nvalid > 64) nvalid = 64;
  float* zb = aggf + (size_t)nbase*AGS;
  for (int idx2 = tid; idx2 < nvalid*AGS; idx2 += 256) zb[idx2] = 0.0f;
}

// ---------------- launcher ----------------
extern "C" void kernel_launch(void* const* d_in, const int* in_sizes, int n_in,
                              void* d_out, int out_size, void* d_ws, size_t ws_size,
                              hipStream_t stream)
{
  const float* his  = (const float*)d_in[0];
  const float* loc  = (const float*)d_in[1];
  const int*   edges= (const int*)d_in[2];
  const float* vel0 = (const float*)d_in[3];
  const float* eatt = (const float*)d_in[4];
  const float* embW = (const float*)d_in[5];
  const float* embB = (const float*)d_in[6];
  const float* eW1  = (const float*)d_in[7];
  const float* eB1  = (const float*)d_in[8];
  const float* eW2  = (const float*)d_in[9];
  const float* eB2  = (const float*)d_in[10];
  const float* cW1  = (const float*)d_in[11];
  const float* cB1  = (const float*)d_in[12];
  const float* cW2  = (const float*)d_in[13];
  const float* vW1  = (const float*)d_in[14];
  const float* vB1  = (const float*)d_in[15];
  const float* vW2  = (const float*)d_in[16];
  const float* vB2  = (const float*)d_in[17];
  const float* nW1  = (const float*)d_in[18];
  const float* nB1  = (const float*)d_in[19];
  const float* nW2  = (const float*)d_in[20];
  const float* nB2  = (const float*)d_in[21];
  const int* erow = edges;
  const int* ecol = edges + EE;

  char* ws = (char*)d_ws;
  size_t off = 0;
  auto alloc = [&](size_t bytes)->char*{
    char* p = ws + off;
    off = (off + bytes + 255) & ~(size_t)255;
    return p;
  };
  ushort* hb     = (ushort*)alloc((size_t)NN*HD*2);
  int*    counts = (int*)   alloc((size_t)NN*4);
  int*    cursor = (int*)   alloc((size_t)NN*4);
  int*    bsum   = (int*)   alloc(256*4);
  int*    bbase  = (int*)   alloc(256*4);
  float4* coordw4= (float4*)alloc((size_t)NN*16);
  float4* velw4  = (float4*)alloc((size_t)NN*16);
  float*  aggf   = (float*) alloc((size_t)NN*AGS*4);
  ushort* allp   = (ushort*)alloc(33792*2);
  int4*   erec   = (int4*)  alloc((size_t)EE*16);

  ushort* eW1p32 = allp;            // 9216
  ushort* eW2p32 = allp + 9216;     // 4096
  ushort* cW1p32 = allp + 13312;    // 4096
  ushort* nW1p   = allp + 17408;    // 8192
  ushort* nW2p   = allp + 25600;    // 4096
  ushort* vW1p   = allp + 29696;    // 4096

  float* xout = (float*)d_out;                    // [N,3]
  float* hout = (float*)d_out + (size_t)NN*3;     // [N,64] — doubles as fp32 h buffer
  float* vout = (float*)d_out + (size_t)NN*3 + (size_t)NN*HD; // [N,3]

  hipMemsetAsync(counts, 0, (size_t)NN*4, stream);
  hipMemsetAsync(aggf, 0, (size_t)NN*AGS*4, stream);
  k_count2<<<3125,256,0,stream>>>(erow, counts, loc, vel0, coordw4, velw4);
  k_bsum<<<196,256,0,stream>>>(counts, bsum);
  k_bscan<<<1,256,0,stream>>>(bsum, bbase);
  k_scatter<<<196,256,0,stream>>>(counts, bbase, cursor);
  k_fill<<<3125,256,0,stream>>>(erow, ecol, eatt, cursor, erec);
  k_packall<<<132,256,0,stream>>>(eW1, eB1, eW2, cW1, nW1, nW2, vW1, allp);
  k_embed<<<12500,256,0,stream>>>(his, embW, embB, hout, hb);

  for (int L = 0; L < 4; ++L){
    k_edge<<<6250,256,0,stream>>>(hb, coordw4, erec,
        eW1p32, eW2p32, cW1p32, eB2, cB1, cW2, aggf);
    k_node<<<782,256,0,stream>>>(hb, aggf, hout, nW1p, nW2p, vW1p,
        nB1, nB2, vB1, vW2, vB2, counts, velw4, coordw4,
        hout, hb, xout, vout, (L==3) ? 1 : 0);
  }
}